// Round 15
// baseline (947.710 us; speedup 1.0000x reference)
//
#include <hip/hip_runtime.h>
#include <cstdint>
#include <cstddef>

#define NN      20000
#define RR      4
#define EE      40000
#define CIN     256
#define CEDGE   128
#define HIDW    512
#define OUTW    256
#define NH      8
#define MEDGE   (RR*EE)
#define SCALEF  0.125f

typedef unsigned short u16;
typedef short s8v  __attribute__((ext_vector_type(8)));
typedef float f32x4 __attribute__((ext_vector_type(4)));

// ---- ws layout (BYTE offsets) ----
#define B_KQV   10240000ull             // 20000*1536*2 = 61,440,000
#define B_KREL  71680000ull             // 20000*2048*2 = 81,920,000 (qW; wsum2 overlays row-exclusively)
#define B_AGG   153600000ull            // 20000*512*2
#define B_H0    174080000ull            // 20000*512*2
#define B_H1    194560000ull            // 20000*512*2
#define B_LSE   220160000ull            // fillcnt overlay during CSR build
#define B_ROWP  220800000ull            // 20001*4 -> pad
#define B_EREC  220880128ull            // 160000*4
#define B_WTS   221520128ull            // bf16 weights, ~5.2 MB
#define WS_NEED 227000000ull

__device__ __forceinline__ u16 f2b(float f) {
    unsigned u = __float_as_uint(f);
    unsigned r = (u + 0x7FFFu + ((u >> 16) & 1u)) >> 16;
    return (u16)r;
}
__device__ __forceinline__ float b2f(u16 h) { return __uint_as_float(((unsigned)h) << 16); }
__device__ __forceinline__ float gelu_exact(float x) {
    return 0.5f * x * (1.0f + erff(x * 0.70710678118654752f));
}

// async global->LDS, 16 bytes per lane; LDS dest must be wave-uniform base
__device__ __forceinline__ void gl_lds16(const u16* g, u16* l) {
    __builtin_amdgcn_global_load_lds(
        (const __attribute__((address_space(1))) void*)g,
        (__attribute__((address_space(3))) void*)l, 16, 0, 0);
}

// =============== generic bf16 MFMA GEMM (R6 single-buffered version, proven) ===============
template<int BN, int ACT, bool OUTBF16, bool BIAS, bool SKIP, bool AF32 = false>
__global__ __launch_bounds__(256) void gemm_bf16(
    const void* __restrict__ Av, int lda, size_t astride,
    const u16* __restrict__ BT, int ldb, size_t bstride,
    const float* __restrict__ bias,
    void* __restrict__ Cv, int ldc, size_t cstride,
    int M, int K,
    const u16* __restrict__ skipx, const float* __restrict__ gatep)
{
    constexpr int FN = BN / 32;
    constexpr int BI = BN / 32;
    __shared__ __align__(16) u16 As[128 * 64];
    __shared__ __align__(16) u16 Bs[BN * 64];

    const int t = threadIdx.x, lane = t & 63, wid = t >> 6;
    const int m0 = blockIdx.y * 128, n0 = blockIdx.x * BN;
    const int z  = blockIdx.z;
    const u16*   Bz = BT + (size_t)z * bstride;
    const float* Af = (const float*)Av + (AF32 ? (size_t)z * astride : 0);
    const u16*   Au = (const u16*)Av   + (AF32 ? 0 : (size_t)z * astride);
    const int wm = wid >> 1, wn = wid & 1;

    const int srow   = lane >> 3;
    const int schunk = (lane & 7) ^ srow;

    f32x4 acc[4][FN];
    #pragma unroll
    for (int i = 0; i < 4; ++i)
        #pragma unroll
        for (int j = 0; j < FN; ++j)
            acc[i][j] = (f32x4){0.f, 0.f, 0.f, 0.f};

    for (int k0 = 0; k0 < K; k0 += 64) {
        if (AF32) {
            #pragma unroll
            for (int i = 0; i < 4; ++i) {
                int c = i * 256 + t;
                int row = c >> 3, cc = c & 7;
                int gr = m0 + row; gr = gr < M ? gr : M - 1;
                const float* Ap = Af + (size_t)gr * lda + k0 + cc * 8;
                float4 p = *(const float4*)Ap;
                float4 q = *(const float4*)(Ap + 4);
                s8v v;
                v[0] = (short)f2b(p.x); v[1] = (short)f2b(p.y);
                v[2] = (short)f2b(p.z); v[3] = (short)f2b(p.w);
                v[4] = (short)f2b(q.x); v[5] = (short)f2b(q.y);
                v[6] = (short)f2b(q.z); v[7] = (short)f2b(q.w);
                *(s8v*)&As[row * 64 + ((cc ^ (row & 7)) << 3)] = v;
            }
        } else {
            #pragma unroll
            for (int i = 0; i < 4; ++i) {
                int t4 = wid * 4 + i;
                int row = t4 * 8 + srow;
                int gr = m0 + row; gr = gr < M ? gr : M - 1;
                gl_lds16(Au + (size_t)gr * lda + k0 + schunk * 8, &As[t4 * 512]);
            }
        }
        #pragma unroll
        for (int i = 0; i < BI; ++i) {
            int tb = wid * BI + i;
            int col = n0 + tb * 8 + srow;
            gl_lds16(Bz + (size_t)col * ldb + k0 + schunk * 8, &Bs[tb * 512]);
        }
        __syncthreads();
        #pragma unroll
        for (int ks = 0; ks < 2; ++ks) {
            s8v af[4], bf[FN];
            #pragma unroll
            for (int i = 0; i < 4; ++i) {
                int arow = wm * 64 + i * 16 + (lane & 15);
                int ac   = (ks * 4 + (lane >> 4)) ^ (lane & 7);
                af[i] = *(const s8v*)&As[arow * 64 + ac * 8];
            }
            #pragma unroll
            for (int j = 0; j < FN; ++j) {
                int brow = wn * (BN / 2) + j * 16 + (lane & 15);
                int bc   = (ks * 4 + (lane >> 4)) ^ (lane & 7);
                bf[j] = *(const s8v*)&Bs[brow * 64 + bc * 8];
            }
            #pragma unroll
            for (int i = 0; i < 4; ++i)
                #pragma unroll
                for (int j = 0; j < FN; ++j)
                    acc[i][j] = __builtin_amdgcn_mfma_f32_16x16x32_bf16(af[i], bf[j], acc[i][j], 0, 0, 0);
        }
        __syncthreads();
    }

    float gate = 1.f, ogate = 0.f;
    if (SKIP) { float s = *gatep; gate = 1.f / (1.f + expf(-s)); ogate = 1.f - gate; }
    u16*   Cb = (u16*)Cv   + (size_t)z * cstride;
    float* Cf = (float*)Cv + (size_t)z * cstride;
    #pragma unroll
    for (int i = 0; i < 4; ++i) {
        int rbase = m0 + wm * 64 + i * 16 + (lane >> 4) * 4;
        #pragma unroll
        for (int j = 0; j < FN; ++j) {
            int col = n0 + wn * (BN / 2) + j * 16 + (lane & 15);
            float bv = BIAS ? bias[col] : 0.f;
            #pragma unroll
            for (int q = 0; q < 4; ++q) {
                int r = rbase + q;
                if (r >= M) continue;
                float v = acc[i][j][q] + bv;
                if (ACT == 1) v = fmaxf(v, 0.f);
                if (ACT == 2) v = gelu_exact(v);
                if (SKIP) v = gate * v + ogate * b2f(skipx[(size_t)r * ldc + col]);
                if (OUTBF16) Cb[(size_t)r * ldc + col] = f2b(v);
                else         Cf[(size_t)r * ldc + col] = v;
            }
        }
    }
}

// =============== fused edge MLP v5 — 128 rows, 8 waves; transposed stage-1 output ===============
__global__ __launch_bounds__(512) void edge_mlp(
    const float* __restrict__ ea, const u16* __restrict__ We1T,
    const float* __restrict__ b1, const u16* __restrict__ We2T,
    const float* __restrict__ b2, float* __restrict__ out)
{
    __shared__ __align__(16) u16 Ae[128 * 128];
    __shared__ __align__(16) u16 Ic[128 * 128];

    const int t = threadIdx.x, lane = t & 63, w = t >> 6;   // w 0..7
    const int e0 = blockIdx.x * 128;
    const int l15 = lane & 15, l4 = lane >> 4;

    s8v w1f[4];
    auto loadW1 = [&](s8v* dst, int c) {
        #pragma unroll
        for (int ks = 0; ks < 4; ++ks) {
            int col1 = c * 128 + w * 16 + l15;
            dst[ks] = *(const s8v*)(We1T + (size_t)col1 * 128 + ks * 32 + l4 * 8);
        }
    };
    loadW1(w1f, 0);

    #pragma unroll
    for (int i = 0; i < 8; ++i) {
        int f   = i * 512 + t;
        int row = f >> 5;
        int c4  = f & 31;
        float4 p = *(const float4*)(ea + (size_t)(e0 + row) * 128 + c4 * 4);
        unsigned lo = (unsigned)f2b(p.x) | ((unsigned)f2b(p.y) << 16);
        unsigned hi = (unsigned)f2b(p.z) | ((unsigned)f2b(p.w) << 16);
        int chunk = c4 >> 1;
        int sub   = (c4 & 1) * 8;
        *(uint2*)((char*)Ae + row * 256 + ((chunk ^ (row & 7)) << 4) + sub)
            = make_uint2(lo, hi);
    }
    __syncthreads();

    f32x4 acc2[8][2];
    #pragma unroll
    for (int m = 0; m < 8; ++m) {
        acc2[m][0] = (f32x4){0.f, 0.f, 0.f, 0.f};
        acc2[m][1] = (f32x4){0.f, 0.f, 0.f, 0.f};
    }

    #pragma unroll
    for (int c = 0; c < 4; ++c) {
        f32x4 sacc[8];
        #pragma unroll
        for (int m = 0; m < 8; ++m) sacc[m] = (f32x4){0.f, 0.f, 0.f, 0.f};
        #pragma unroll
        for (int ks = 0; ks < 4; ++ks) {
            #pragma unroll
            for (int m = 0; m < 8; ++m) {
                int row = m * 16 + l15;
                int kc  = (ks * 4 + l4) ^ (row & 7);
                s8v af = *(const s8v*)&Ae[row * 128 + kc * 8];
                sacc[m] = __builtin_amdgcn_mfma_f32_16x16x32_bf16(w1f[ks], af, sacc[m], 0, 0, 0);
            }
        }
        s8v w2f[4][2];
        #pragma unroll
        for (int ks = 0; ks < 4; ++ks)
            #pragma unroll
            for (int n = 0; n < 2; ++n) {
                int col = w * 32 + n * 16 + l15;
                w2f[ks][n] = *(const s8v*)(We2T + (size_t)col * 512 + c * 128 + ks * 32 + l4 * 8);
            }
        __syncthreads();
        {
            const float4 bv4 = *(const float4*)(b1 + c * 128 + w * 16 + l4 * 4);
            int icol  = w * 16 + l4 * 4;
            int chunk = icol >> 3, sub = icol & 7;
            #pragma unroll
            for (int m = 0; m < 8; ++m) {
                int row = m * 16 + l15;
                u16 p0 = f2b(fmaxf(sacc[m][0] + bv4.x, 0.f));
                u16 p1 = f2b(fmaxf(sacc[m][1] + bv4.y, 0.f));
                u16 p2 = f2b(fmaxf(sacc[m][2] + bv4.z, 0.f));
                u16 p3 = f2b(fmaxf(sacc[m][3] + bv4.w, 0.f));
                unsigned lo = (unsigned)p0 | ((unsigned)p1 << 16);
                unsigned hi = (unsigned)p2 | ((unsigned)p3 << 16);
                *(uint2*)((char*)Ic + row * 256 + ((chunk ^ (row & 7)) << 4) + sub * 2)
                    = make_uint2(lo, hi);
            }
        }
        if (c < 3) loadW1(w1f, c + 1);
        __syncthreads();
        #pragma unroll
        for (int ks = 0; ks < 4; ++ks) {
            #pragma unroll
            for (int m = 0; m < 8; ++m) {
                int row = m * 16 + l15;
                int kc  = (ks * 4 + l4) ^ (row & 7);
                s8v af = *(const s8v*)&Ic[row * 128 + kc * 8];
                acc2[m][0] = __builtin_amdgcn_mfma_f32_16x16x32_bf16(af, w2f[ks][0], acc2[m][0], 0, 0, 0);
                acc2[m][1] = __builtin_amdgcn_mfma_f32_16x16x32_bf16(af, w2f[ks][1], acc2[m][1], 0, 0, 0);
            }
        }
    }

    #pragma unroll
    for (int n = 0; n < 2; ++n) {
        int col = w * 32 + n * 16 + l15;
        float bv = b2[col];
        #pragma unroll
        for (int m = 0; m < 8; ++m)
            #pragma unroll
            for (int q = 0; q < 4; ++q) {
                int row = m * 16 + l4 * 4 + q;
                out[(size_t)(e0 + row) * 256 + col] = acc2[m][n][q] + bv;
            }
    }
}

// =============== weight conversions ===============
__global__ __launch_bounds__(256) void transpose_f2b(
    const float* __restrict__ W, u16* __restrict__ WT, int K, int N)
{
    __shared__ float tile[32][33];
    int kb = blockIdx.x * 32, nb = blockIdx.y * 32;
    int tx = threadIdx.x & 31, ty = threadIdx.x >> 5;
    #pragma unroll
    for (int i = 0; i < 32; i += 8)
        tile[ty + i][tx] = W[(size_t)(kb + ty + i) * N + nb + tx];
    __syncthreads();
    #pragma unroll
    for (int i = 0; i < 32; i += 8)
        WT[(size_t)(nb + ty + i) * K + kb + tx] = f2b(tile[tx][ty + i]);
}

// Wk[r][h][d][e] -> WkT2[h][r*64+d][e]   (B^T for the qW GEMM: contract over e)
__global__ void conv_wk2(const float* __restrict__ Wk, u16* __restrict__ WkT2)
{
    int idx = blockIdx.x * 256 + threadIdx.x;
    if (idx >= 8 * 256 * 64) return;
    int e = idx & 63, rd = (idx >> 6) & 255, h = idx >> 14;
    int d = rd & 63, r = rd >> 6;
    WkT2[idx] = f2b(Wk[(size_t)(((r * 8 + h) * 64 + d) * 64) + e]);
}

// Wv[r][h][d][e] -> WvT[h][e][r*64+d]
__global__ void conv_wv(const float* __restrict__ Wv, u16* __restrict__ WvT)
{
    int idx = blockIdx.x * 256 + threadIdx.x;
    if (idx >= 8 * 64 * 256) return;
    int d = idx & 63, r = (idx >> 6) & 3, e = (idx >> 8) & 63, h = idx >> 14;
    WvT[idx] = f2b(Wv[(size_t)(((r * 8 + h) * 64 + d) * 64) + e]);
}

// =============== CSR build (R11-exact) ===============
__global__ void deg_kernel(const int* __restrict__ ei, int* __restrict__ rowptr)
{
    int idx = blockIdx.x * 256 + threadIdx.x;
    if (idx >= MEDGE) return;
    int r = idx / EE;
    atomicAdd(&rowptr[ei[idx + (r + 1) * EE]], 1);
}

__global__ __launch_bounds__(256) void scan_kernel(int* __restrict__ rowptr)
{
    __shared__ int buf[256];
    __shared__ int carry;
    const int t = threadIdx.x;
    if (t == 0) carry = 0;
    __syncthreads();
    for (int base = 0; base < NN; base += 256) {
        int i = base + t;
        int v = (i < NN) ? rowptr[i] : 0;
        buf[t] = v;
        __syncthreads();
        for (int off = 1; off < 256; off <<= 1) {
            int tv = (t >= off) ? buf[t - off] : 0;
            __syncthreads();
            buf[t] += tv;
            __syncthreads();
        }
        int total = buf[255];
        int excl = buf[t] - v;
        int c = carry;
        __syncthreads();
        if (i < NN) rowptr[i] = c + excl;
        if (t == 0) carry = c + total;
        __syncthreads();
    }
    if (t == 0) rowptr[NN] = carry;
}

__global__ void fill_kernel(const int* __restrict__ ei, const int* __restrict__ rowptr,
                            int* __restrict__ fillcnt, int* __restrict__ erec)
{
    int idx = blockIdx.x * 256 + threadIdx.x;
    if (idx >= MEDGE) return;
    int r = idx / EE;
    int dst = ei[idx + (r + 1) * EE];
    int pos = rowptr[dst] + atomicAdd(&fillcnt[dst], 1);
    erec[pos] = idx;
}

// =============== single-pass fused gather v4: no-max softmax, PAIRED edge chains ===============
// Associative reduction (no running max) -> edges can be processed in independent pairs:
// both edges' load chains issued before compute, doubling per-wave outstanding loads.
__global__ __launch_bounds__(256) void gather_attn(
    const u16* __restrict__ kqvb, const u16* __restrict__ qW,
    const int* __restrict__ ei, const int* __restrict__ rowptr,
    const int* __restrict__ erec, const float* __restrict__ prel,
    u16* __restrict__ wsum2)
{
    int n    = (blockIdx.x * 256 + threadIdx.x) >> 6;
    int lane = threadIdx.x & 63;
    if (n >= NN) return;
    int p0 = rowptr[n], p1 = rowptr[n + 1];
    int h = lane >> 3, sub = lane & 7;

    float qf0[8], qf1[8], qf2[8], qf3[8];
    {
        const u16* qp = qW + (size_t)n * 2048 + h * 256 + sub * 8;
        s8v v0 = *(const s8v*)(qp + 0);
        s8v v1 = *(const s8v*)(qp + 64);
        s8v v2 = *(const s8v*)(qp + 128);
        s8v v3 = *(const s8v*)(qp + 192);
        #pragma unroll
        for (int q = 0; q < 8; ++q) {
            qf0[q] = b2f((u16)v0[q]); qf1[q] = b2f((u16)v1[q]);
            qf2[q] = b2f((u16)v2[q]); qf3[q] = b2f((u16)v3[q]);
        }
    }
    const float LSC = SCALEF * 1.44269504088896f;
    float pr0 = prel[0 * NH + h] * LSC, pr1 = prel[1 * NH + h] * LSC;
    float pr2 = prel[2 * NH + h] * LSC, pr3 = prel[3 * NH + h] * LSC;

    float ssum = 0.f;
    float a0[8] = {}, a1[8] = {}, a2[8] = {}, a3[8] = {};

    auto dotq = [&](s8v kv, int r) -> float {        // r is wave-uniform
        float s = 0.f;
        if (r == 0) {
            #pragma unroll
            for (int q = 0; q < 8; ++q) s += b2f((u16)kv[q]) * qf0[q];
        } else if (r == 1) {
            #pragma unroll
            for (int q = 0; q < 8; ++q) s += b2f((u16)kv[q]) * qf1[q];
        } else if (r == 2) {
            #pragma unroll
            for (int q = 0; q < 8; ++q) s += b2f((u16)kv[q]) * qf2[q];
        } else {
            #pragma unroll
            for (int q = 0; q < 8; ++q) s += b2f((u16)kv[q]) * qf3[q];
        }
        s += __shfl_xor(s, 1); s += __shfl_xor(s, 2); s += __shfl_xor(s, 4);
        return s;
    };
    auto prw = [&](int r) -> float {
        return (r == 0) ? pr0 : (r == 1) ? pr1 : (r == 2) ? pr2 : pr3;
    };
    auto accum = [&](float w, s8v vv, int r) {       // r wave-uniform
        if (r == 0) {
            #pragma unroll
            for (int q = 0; q < 8; ++q) a0[q] += w * b2f((u16)vv[q]);
        } else if (r == 1) {
            #pragma unroll
            for (int q = 0; q < 8; ++q) a1[q] += w * b2f((u16)vv[q]);
        } else if (r == 2) {
            #pragma unroll
            for (int q = 0; q < 8; ++q) a2[q] += w * b2f((u16)vv[q]);
        } else {
            #pragma unroll
            for (int q = 0; q < 8; ++q) a3[q] += w * b2f((u16)vv[q]);
        }
    };

    int j = p0;
    for (; j + 1 < p1; j += 2) {
        // issue BOTH edges' chains before any compute
        int idxA = erec[j], idxB = erec[j + 1];
        int rA = idxA / EE, rB = idxB / EE;
        int srcA = ei[idxA + rA * EE], srcB = ei[idxB + rB * EE];
        const u16* rowA = kqvb + (size_t)srcA * 1536;
        const u16* rowB = kqvb + (size_t)srcB * 1536;
        s8v kvA = *(const s8v*)(rowA + h * 64 + sub * 8);
        s8v vvA = *(const s8v*)(rowA + 1024 + lane * 8);
        s8v kvB = *(const s8v*)(rowB + h * 64 + sub * 8);
        s8v vvB = *(const s8v*)(rowB + 1024 + lane * 8);
        float wA = exp2f(dotq(kvA, rA) * prw(rA));
        float wB = exp2f(dotq(kvB, rB) * prw(rB));
        ssum += wA; ssum += wB;
        accum(wA, vvA, rA);
        accum(wB, vvB, rB);
    }
    if (j < p1) {
        int idxA = erec[j];
        int rA = idxA / EE;
        int srcA = ei[idxA + rA * EE];
        const u16* rowA = kqvb + (size_t)srcA * 1536;
        s8v kvA = *(const s8v*)(rowA + h * 64 + sub * 8);
        s8v vvA = *(const s8v*)(rowA + 1024 + lane * 8);
        float wA = exp2f(dotq(kvA, rA) * prw(rA));
        ssum += wA;
        accum(wA, vvA, rA);
    }

    float inv = 1.0f / (ssum + 1e-16f);
    u16* base = wsum2 + (size_t)n * 2048 + h * 256 + sub * 8;
    s8v o;
    #pragma unroll
    for (int q = 0; q < 8; ++q) o[q] = (short)f2b(a0[q] * inv);
    *(s8v*)(base + 0)   = o;
    #pragma unroll
    for (int q = 0; q < 8; ++q) o[q] = (short)f2b(a1[q] * inv);
    *(s8v*)(base + 64)  = o;
    #pragma unroll
    for (int q = 0; q < 8; ++q) o[q] = (short)f2b(a2[q] * inv);
    *(s8v*)(base + 128) = o;
    #pragma unroll
    for (int q = 0; q < 8; ++q) o[q] = (short)f2b(a3[q] * inv);
    *(s8v*)(base + 192) = o;
}

extern "C" void kernel_launch(void* const* d_in, const int* in_sizes, int n_in,
                              void* d_out, int out_size, void* d_ws, size_t ws_size,
                              hipStream_t stream)
{
    const float* x    = (const float*)d_in[0];
    const int*   ei   = (const int*)d_in[1];
    const float* ea   = (const float*)d_in[2];
    const float* Wkqv[2] = {(const float*)d_in[3],  (const float*)d_in[10]};
    const float* bkqv[2] = {(const float*)d_in[4],  (const float*)d_in[11]};
    const float* Wk[2]   = {(const float*)d_in[5],  (const float*)d_in[12]};
    const float* Wv[2]   = {(const float*)d_in[6],  (const float*)d_in[13]};
    const float* prel[2] = {(const float*)d_in[7],  (const float*)d_in[14]};
    const float* Wout[2] = {(const float*)d_in[8],  (const float*)d_in[15]};
    const float* bout[2] = {(const float*)d_in[9],  (const float*)d_in[16]};
    const float* skip1 = (const float*)d_in[17];
    const float* Wfc   = (const float*)d_in[18];
    const float* bfc   = (const float*)d_in[19];
    const float* We1   = (const float*)d_in[20];
    const float* be1   = (const float*)d_in[21];
    const float* We2   = (const float*)d_in[22];
    const float* be2   = (const float*)d_in[23];

    if (ws_size < WS_NEED) return;

    char* wsb = (char*)d_ws;
    u16*   kqvb  = (u16*)(wsb + B_KQV);
    u16*   qWbuf = (u16*)(wsb + B_KREL);     // qW; wsum2 overlays row-exclusively
    u16*   aggb  = (u16*)(wsb + B_AGG);
    u16*   h0b   = (u16*)(wsb + B_H0);
    u16*   h1b   = (u16*)(wsb + B_H1);
    int*   fillcnt = (int*)(wsb + B_LSE);    // build-time overlay
    int*   rowptr  = (int*)(wsb + B_ROWP);
    int*   erec    = (int*)(wsb + B_EREC);
    float* outf  = (float*)d_out;

    // bf16 weight arena
    u16* wt = (u16*)(wsb + B_WTS);
    u16* WkqvT[2] = {wt, wt + 393216};              wt += 393216 + 786432;
    u16* WkT2[2]  = {wt, wt + 131072};              wt += 262144;
    u16* WvT[2]   = {wt, wt + 131072};              wt += 262144;
    u16* WoutT[2] = {wt, wt + 262144};              wt += 524288;
    u16* WfcT     = wt;                             wt += 131072;
    u16* We1T     = wt;                             wt += 65536;
    u16* We2T     = wt;

    const dim3 blk(256);
    const int mt128  = (NN + 127) / 128;   // 157

    // ---- weight conversions ----
    transpose_f2b<<<dim3(CIN / 32, 1536 / 32), blk, 0, stream>>>(Wkqv[0], WkqvT[0], CIN, 1536);
    transpose_f2b<<<dim3(HIDW / 32, 1536 / 32), blk, 0, stream>>>(Wkqv[1], WkqvT[1], HIDW, 1536);
    transpose_f2b<<<dim3(HIDW / 32, HIDW / 32), blk, 0, stream>>>(Wout[0], WoutT[0], HIDW, HIDW);
    transpose_f2b<<<dim3(HIDW / 32, HIDW / 32), blk, 0, stream>>>(Wout[1], WoutT[1], HIDW, HIDW);
    transpose_f2b<<<dim3(HIDW / 32, OUTW / 32), blk, 0, stream>>>(Wfc, WfcT, HIDW, OUTW);
    transpose_f2b<<<dim3(CEDGE / 32, HIDW / 32), blk, 0, stream>>>(We1, We1T, CEDGE, HIDW);
    transpose_f2b<<<dim3(HIDW / 32, OUTW / 32), blk, 0, stream>>>(We2, We2T, HIDW, OUTW);
    for (int l = 0; l < 2; ++l) {
        conv_wk2<<<(131072 + 255) / 256, blk, 0, stream>>>(Wk[l], WkT2[l]);
        conv_wv<<<(131072 + 255) / 256, blk, 0, stream>>>(Wv[l], WvT[l]);
    }

    // ---- CSR build ----
    hipMemsetAsync(rowptr, 0, (NN + 1) * sizeof(int), stream);
    hipMemsetAsync(fillcnt, 0, NN * sizeof(int), stream);
    deg_kernel<<<(MEDGE + 255) / 256, blk, 0, stream>>>(ei, rowptr);
    scan_kernel<<<1, blk, 0, stream>>>(rowptr);
    fill_kernel<<<(MEDGE + 255) / 256, blk, 0, stream>>>(ei, rowptr, fillcnt, erec);

    for (int l = 0; l < 2; ++l) {
        int K = (l == 0) ? CIN : HIDW;

        // kqv = xin @ Wkqv + b  -> bf16 [20000 x 1536]
        if (l == 0)
            gemm_bf16<128, 0, true, true, false, true><<<dim3(12, mt128), blk, 0, stream>>>(
                (const void*)x, K, 0, WkqvT[0], K, 0, bkqv[0], kqvb, 1536, 0, NN, K, nullptr, nullptr);
        else
            gemm_bf16<128, 0, true, true, false><<<dim3(12, mt128), blk, 0, stream>>>(
                (const void*)h0b, K, 0, WkqvT[1], K, 0, bkqv[1], kqvb, 1536, 0, NN, K, nullptr, nullptr);

        // qW (all relations): per-head batched GEMM over q slice; out [n][h*256 + r*64 + d]
        gemm_bf16<128, 0, true, false, false><<<dim3(2, mt128, NH), blk, 0, stream>>>(
            (const void*)(kqvb + 512), 1536, 64, WkT2[l], 64, (size_t)256 * 64, nullptr,
            qWbuf, 2048, 256, NN, 64, nullptr, nullptr);

        // single-pass fused gather (wsum2 overlays qW row-exclusively)
        gather_attn<<<(NN * 64) / 256, blk, 0, stream>>>(
            kqvb, qWbuf, ei, rowptr, erec, prel[l], qWbuf);

        // agg = gelu( sum_r wsum_r @ Wv_r ) : per-head batched GEMM, K=256, N=64
        gemm_bf16<64, 2, true, false, false><<<dim3(1, mt128, NH), blk, 0, stream>>>(
            (const void*)qWbuf, 2048, 256, WvT[l], 256, (size_t)64 * 256, nullptr,
            aggb, 512, 64, NN, 256, nullptr, nullptr);

        // out = agg @ Wout + bout (+ skip mix on layer 1)
        if (l == 0)
            gemm_bf16<128, 0, true, true, false><<<dim3(4, mt128), blk, 0, stream>>>(
                (const void*)aggb, 512, 0, WoutT[0], 512, 0, bout[0], h0b, 512, 0, NN, 512, nullptr, nullptr);
        else
            gemm_bf16<128, 0, true, true, true><<<dim3(4, mt128), blk, 0, stream>>>(
                (const void*)aggb, 512, 0, WoutT[1], 512, 0, bout[1], h1b, 512, 0, NN, 512, h0b, skip1);
    }

    // node_embeds = h1 @ Wfc + bfc (f32 out)
    gemm_bf16<128, 0, false, true, false><<<dim3(2, mt128), blk, 0, stream>>>(
        (const void*)h1b, 512, 0, WfcT, 512, 0, bfc, outf, 256, 0, NN, 512, nullptr, nullptr);

    // edge_embeds = relu(ea @ We1 + be1) @ We2 + be2 — fused, 128-row / 8-wave blocks
    edge_mlp<<<MEDGE / 128, dim3(512), 0, stream>>>(ea, We1T, be1, We2T, be2, outf + 5120000);
}

// Round 16
// 734.673 us; speedup vs baseline: 1.2900x; 1.2900x over previous
//
#include <hip/hip_runtime.h>
#include <cstdint>
#include <cstddef>

#define NN      20000
#define RR      4
#define EE      40000
#define CIN     256
#define CEDGE   128
#define HIDW    512
#define OUTW    256
#define NH      8
#define MEDGE   (RR*EE)
#define SCALEF  0.125f

typedef unsigned short u16;
typedef short s8v  __attribute__((ext_vector_type(8)));
typedef float f32x4 __attribute__((ext_vector_type(4)));

// ---- ws layout (BYTE offsets) ----
#define B_KQV   10240000ull             // 20000*1536*2 = 61,440,000
#define B_KREL  71680000ull             // 20000*2048*2 = 81,920,000 (qW; wsum2 overlays row-exclusively)
#define B_AGG   153600000ull            // 20000*512*2
#define B_H0    174080000ull            // 20000*512*2
#define B_H1    194560000ull            // 20000*512*2
#define B_LSE   220160000ull            // fillcnt overlay during CSR build
#define B_ROWP  220800000ull            // 20001*4 -> pad
#define B_EREC  220880128ull            // 160000*4
#define B_WTS   221520128ull            // bf16 weights, ~5.2 MB
#define WS_NEED 227000000ull

__device__ __forceinline__ u16 f2b(float f) {
    unsigned u = __float_as_uint(f);
    unsigned r = (u + 0x7FFFu + ((u >> 16) & 1u)) >> 16;
    return (u16)r;
}
__device__ __forceinline__ float b2f(u16 h) { return __uint_as_float(((unsigned)h) << 16); }
__device__ __forceinline__ float gelu_exact(float x) {
    return 0.5f * x * (1.0f + erff(x * 0.70710678118654752f));
}

// async global->LDS, 16 bytes per lane; LDS dest must be wave-uniform base
__device__ __forceinline__ void gl_lds16(const u16* g, u16* l) {
    __builtin_amdgcn_global_load_lds(
        (const __attribute__((address_space(1))) void*)g,
        (__attribute__((address_space(3))) void*)l, 16, 0, 0);
}

// =============== generic bf16 MFMA GEMM (R6 single-buffered version, proven) ===============
template<int BN, int ACT, bool OUTBF16, bool BIAS, bool SKIP, bool AF32 = false>
__global__ __launch_bounds__(256) void gemm_bf16(
    const void* __restrict__ Av, int lda, size_t astride,
    const u16* __restrict__ BT, int ldb, size_t bstride,
    const float* __restrict__ bias,
    void* __restrict__ Cv, int ldc, size_t cstride,
    int M, int K,
    const u16* __restrict__ skipx, const float* __restrict__ gatep)
{
    constexpr int FN = BN / 32;
    constexpr int BI = BN / 32;
    __shared__ __align__(16) u16 As[128 * 64];
    __shared__ __align__(16) u16 Bs[BN * 64];

    const int t = threadIdx.x, lane = t & 63, wid = t >> 6;
    const int m0 = blockIdx.y * 128, n0 = blockIdx.x * BN;
    const int z  = blockIdx.z;
    const u16*   Bz = BT + (size_t)z * bstride;
    const float* Af = (const float*)Av + (AF32 ? (size_t)z * astride : 0);
    const u16*   Au = (const u16*)Av   + (AF32 ? 0 : (size_t)z * astride);
    const int wm = wid >> 1, wn = wid & 1;

    const int srow   = lane >> 3;
    const int schunk = (lane & 7) ^ srow;

    f32x4 acc[4][FN];
    #pragma unroll
    for (int i = 0; i < 4; ++i)
        #pragma unroll
        for (int j = 0; j < FN; ++j)
            acc[i][j] = (f32x4){0.f, 0.f, 0.f, 0.f};

    for (int k0 = 0; k0 < K; k0 += 64) {
        if (AF32) {
            #pragma unroll
            for (int i = 0; i < 4; ++i) {
                int c = i * 256 + t;
                int row = c >> 3, cc = c & 7;
                int gr = m0 + row; gr = gr < M ? gr : M - 1;
                const float* Ap = Af + (size_t)gr * lda + k0 + cc * 8;
                float4 p = *(const float4*)Ap;
                float4 q = *(const float4*)(Ap + 4);
                s8v v;
                v[0] = (short)f2b(p.x); v[1] = (short)f2b(p.y);
                v[2] = (short)f2b(p.z); v[3] = (short)f2b(p.w);
                v[4] = (short)f2b(q.x); v[5] = (short)f2b(q.y);
                v[6] = (short)f2b(q.z); v[7] = (short)f2b(q.w);
                *(s8v*)&As[row * 64 + ((cc ^ (row & 7)) << 3)] = v;
            }
        } else {
            #pragma unroll
            for (int i = 0; i < 4; ++i) {
                int t4 = wid * 4 + i;
                int row = t4 * 8 + srow;
                int gr = m0 + row; gr = gr < M ? gr : M - 1;
                gl_lds16(Au + (size_t)gr * lda + k0 + schunk * 8, &As[t4 * 512]);
            }
        }
        #pragma unroll
        for (int i = 0; i < BI; ++i) {
            int tb = wid * BI + i;
            int col = n0 + tb * 8 + srow;
            gl_lds16(Bz + (size_t)col * ldb + k0 + schunk * 8, &Bs[tb * 512]);
        }
        __syncthreads();
        #pragma unroll
        for (int ks = 0; ks < 2; ++ks) {
            s8v af[4], bf[FN];
            #pragma unroll
            for (int i = 0; i < 4; ++i) {
                int arow = wm * 64 + i * 16 + (lane & 15);
                int ac   = (ks * 4 + (lane >> 4)) ^ (lane & 7);
                af[i] = *(const s8v*)&As[arow * 64 + ac * 8];
            }
            #pragma unroll
            for (int j = 0; j < FN; ++j) {
                int brow = wn * (BN / 2) + j * 16 + (lane & 15);
                int bc   = (ks * 4 + (lane >> 4)) ^ (lane & 7);
                bf[j] = *(const s8v*)&Bs[brow * 64 + bc * 8];
            }
            #pragma unroll
            for (int i = 0; i < 4; ++i)
                #pragma unroll
                for (int j = 0; j < FN; ++j)
                    acc[i][j] = __builtin_amdgcn_mfma_f32_16x16x32_bf16(af[i], bf[j], acc[i][j], 0, 0, 0);
        }
        __syncthreads();
    }

    float gate = 1.f, ogate = 0.f;
    if (SKIP) { float s = *gatep; gate = 1.f / (1.f + expf(-s)); ogate = 1.f - gate; }
    u16*   Cb = (u16*)Cv   + (size_t)z * cstride;
    float* Cf = (float*)Cv + (size_t)z * cstride;
    #pragma unroll
    for (int i = 0; i < 4; ++i) {
        int rbase = m0 + wm * 64 + i * 16 + (lane >> 4) * 4;
        #pragma unroll
        for (int j = 0; j < FN; ++j) {
            int col = n0 + wn * (BN / 2) + j * 16 + (lane & 15);
            float bv = BIAS ? bias[col] : 0.f;
            #pragma unroll
            for (int q = 0; q < 4; ++q) {
                int r = rbase + q;
                if (r >= M) continue;
                float v = acc[i][j][q] + bv;
                if (ACT == 1) v = fmaxf(v, 0.f);
                if (ACT == 2) v = gelu_exact(v);
                if (SKIP) v = gate * v + ogate * b2f(skipx[(size_t)r * ldc + col]);
                if (OUTBF16) Cb[(size_t)r * ldc + col] = f2b(v);
                else         Cf[(size_t)r * ldc + col] = v;
            }
        }
    }
}

// =============== fused edge MLP v5 — 128 rows, 8 waves; transposed stage-1 output ===============
__global__ __launch_bounds__(512) void edge_mlp(
    const float* __restrict__ ea, const u16* __restrict__ We1T,
    const float* __restrict__ b1, const u16* __restrict__ We2T,
    const float* __restrict__ b2, float* __restrict__ out)
{
    __shared__ __align__(16) u16 Ae[128 * 128];
    __shared__ __align__(16) u16 Ic[128 * 128];

    const int t = threadIdx.x, lane = t & 63, w = t >> 6;   // w 0..7
    const int e0 = blockIdx.x * 128;
    const int l15 = lane & 15, l4 = lane >> 4;

    s8v w1f[4];
    auto loadW1 = [&](s8v* dst, int c) {
        #pragma unroll
        for (int ks = 0; ks < 4; ++ks) {
            int col1 = c * 128 + w * 16 + l15;
            dst[ks] = *(const s8v*)(We1T + (size_t)col1 * 128 + ks * 32 + l4 * 8);
        }
    };
    loadW1(w1f, 0);

    #pragma unroll
    for (int i = 0; i < 8; ++i) {
        int f   = i * 512 + t;
        int row = f >> 5;
        int c4  = f & 31;
        float4 p = *(const float4*)(ea + (size_t)(e0 + row) * 128 + c4 * 4);
        unsigned lo = (unsigned)f2b(p.x) | ((unsigned)f2b(p.y) << 16);
        unsigned hi = (unsigned)f2b(p.z) | ((unsigned)f2b(p.w) << 16);
        int chunk = c4 >> 1;
        int sub   = (c4 & 1) * 8;
        *(uint2*)((char*)Ae + row * 256 + ((chunk ^ (row & 7)) << 4) + sub)
            = make_uint2(lo, hi);
    }
    __syncthreads();

    f32x4 acc2[8][2];
    #pragma unroll
    for (int m = 0; m < 8; ++m) {
        acc2[m][0] = (f32x4){0.f, 0.f, 0.f, 0.f};
        acc2[m][1] = (f32x4){0.f, 0.f, 0.f, 0.f};
    }

    #pragma unroll
    for (int c = 0; c < 4; ++c) {
        f32x4 sacc[8];
        #pragma unroll
        for (int m = 0; m < 8; ++m) sacc[m] = (f32x4){0.f, 0.f, 0.f, 0.f};
        #pragma unroll
        for (int ks = 0; ks < 4; ++ks) {
            #pragma unroll
            for (int m = 0; m < 8; ++m) {
                int row = m * 16 + l15;
                int kc  = (ks * 4 + l4) ^ (row & 7);
                s8v af = *(const s8v*)&Ae[row * 128 + kc * 8];
                sacc[m] = __builtin_amdgcn_mfma_f32_16x16x32_bf16(w1f[ks], af, sacc[m], 0, 0, 0);
            }
        }
        s8v w2f[4][2];
        #pragma unroll
        for (int ks = 0; ks < 4; ++ks)
            #pragma unroll
            for (int n = 0; n < 2; ++n) {
                int col = w * 32 + n * 16 + l15;
                w2f[ks][n] = *(const s8v*)(We2T + (size_t)col * 512 + c * 128 + ks * 32 + l4 * 8);
            }
        __syncthreads();
        {
            const float4 bv4 = *(const float4*)(b1 + c * 128 + w * 16 + l4 * 4);
            int icol  = w * 16 + l4 * 4;
            int chunk = icol >> 3, sub = icol & 7;
            #pragma unroll
            for (int m = 0; m < 8; ++m) {
                int row = m * 16 + l15;
                u16 p0 = f2b(fmaxf(sacc[m][0] + bv4.x, 0.f));
                u16 p1 = f2b(fmaxf(sacc[m][1] + bv4.y, 0.f));
                u16 p2 = f2b(fmaxf(sacc[m][2] + bv4.z, 0.f));
                u16 p3 = f2b(fmaxf(sacc[m][3] + bv4.w, 0.f));
                unsigned lo = (unsigned)p0 | ((unsigned)p1 << 16);
                unsigned hi = (unsigned)p2 | ((unsigned)p3 << 16);
                *(uint2*)((char*)Ic + row * 256 + ((chunk ^ (row & 7)) << 4) + sub * 2)
                    = make_uint2(lo, hi);
            }
        }
        if (c < 3) loadW1(w1f, c + 1);
        __syncthreads();
        #pragma unroll
        for (int ks = 0; ks < 4; ++ks) {
            #pragma unroll
            for (int m = 0; m < 8; ++m) {
                int row = m * 16 + l15;
                int kc  = (ks * 4 + l4) ^ (row & 7);
                s8v af = *(const s8v*)&Ic[row * 128 + kc * 8];
                acc2[m][0] = __builtin_amdgcn_mfma_f32_16x16x32_bf16(af, w2f[ks][0], acc2[m][0], 0, 0, 0);
                acc2[m][1] = __builtin_amdgcn_mfma_f32_16x16x32_bf16(af, w2f[ks][1], acc2[m][1], 0, 0, 0);
            }
        }
    }

    #pragma unroll
    for (int n = 0; n < 2; ++n) {
        int col = w * 32 + n * 16 + l15;
        float bv = b2[col];
        #pragma unroll
        for (int m = 0; m < 8; ++m)
            #pragma unroll
            for (int q = 0; q < 4; ++q) {
                int row = m * 16 + l4 * 4 + q;
                out[(size_t)(e0 + row) * 256 + col] = acc2[m][n][q] + bv;
            }
    }
}

// =============== weight conversions ===============
__global__ __launch_bounds__(256) void transpose_f2b(
    const float* __restrict__ W, u16* __restrict__ WT, int K, int N)
{
    __shared__ float tile[32][33];
    int kb = blockIdx.x * 32, nb = blockIdx.y * 32;
    int tx = threadIdx.x & 31, ty = threadIdx.x >> 5;
    #pragma unroll
    for (int i = 0; i < 32; i += 8)
        tile[ty + i][tx] = W[(size_t)(kb + ty + i) * N + nb + tx];
    __syncthreads();
    #pragma unroll
    for (int i = 0; i < 32; i += 8)
        WT[(size_t)(nb + ty + i) * K + kb + tx] = f2b(tile[tx][ty + i]);
}

// Wk[r][h][d][e] -> WkT2[h][r*64+d][e]   (B^T for the qW GEMM: contract over e)
__global__ void conv_wk2(const float* __restrict__ Wk, u16* __restrict__ WkT2)
{
    int idx = blockIdx.x * 256 + threadIdx.x;
    if (idx >= 8 * 256 * 64) return;
    int e = idx & 63, rd = (idx >> 6) & 255, h = idx >> 14;
    int d = rd & 63, r = rd >> 6;
    WkT2[idx] = f2b(Wk[(size_t)(((r * 8 + h) * 64 + d) * 64) + e]);
}

// Wv[r][h][d][e] -> WvT[h][e][r*64+d]
__global__ void conv_wv(const float* __restrict__ Wv, u16* __restrict__ WvT)
{
    int idx = blockIdx.x * 256 + threadIdx.x;
    if (idx >= 8 * 64 * 256) return;
    int d = idx & 63, r = (idx >> 6) & 3, e = (idx >> 8) & 63, h = idx >> 14;
    WvT[idx] = f2b(Wv[(size_t)(((r * 8 + h) * 64 + d) * 64) + e]);
}

// =============== CSR build (R11-exact) ===============
__global__ void deg_kernel(const int* __restrict__ ei, int* __restrict__ rowptr)
{
    int idx = blockIdx.x * 256 + threadIdx.x;
    if (idx >= MEDGE) return;
    int r = idx / EE;
    atomicAdd(&rowptr[ei[idx + (r + 1) * EE]], 1);
}

__global__ __launch_bounds__(256) void scan_kernel(int* __restrict__ rowptr)
{
    __shared__ int buf[256];
    __shared__ int carry;
    const int t = threadIdx.x;
    if (t == 0) carry = 0;
    __syncthreads();
    for (int base = 0; base < NN; base += 256) {
        int i = base + t;
        int v = (i < NN) ? rowptr[i] : 0;
        buf[t] = v;
        __syncthreads();
        for (int off = 1; off < 256; off <<= 1) {
            int tv = (t >= off) ? buf[t - off] : 0;
            __syncthreads();
            buf[t] += tv;
            __syncthreads();
        }
        int total = buf[255];
        int excl = buf[t] - v;
        int c = carry;
        __syncthreads();
        if (i < NN) rowptr[i] = c + excl;
        if (t == 0) carry = c + total;
        __syncthreads();
    }
    if (t == 0) rowptr[NN] = carry;
}

__global__ void fill_kernel(const int* __restrict__ ei, const int* __restrict__ rowptr,
                            int* __restrict__ fillcnt, int* __restrict__ erec)
{
    int idx = blockIdx.x * 256 + threadIdx.x;
    if (idx >= MEDGE) return;
    int r = idx / EE;
    int dst = ei[idx + (r + 1) * EE];
    int pos = rowptr[dst] + atomicAdd(&fillcnt[dst], 1);
    erec[pos] = idx;
}

// =============== single-pass fused gather v5: no-max softmax + scalar index prefetch ===============
// R14 loop body (proven spill-free) + one-ahead prefetch of the SCALAR index chain only
// (erec[j+1] -> r -> src; +3 VGPRs). The 2-load index prefix of iteration j+1 overlaps
// iteration j's kv/vv loads and compute; accumulation order identical to R14.
__global__ __launch_bounds__(256) void gather_attn(
    const u16* __restrict__ kqvb, const u16* __restrict__ qW,
    const int* __restrict__ ei, const int* __restrict__ rowptr,
    const int* __restrict__ erec, const float* __restrict__ prel,
    u16* __restrict__ wsum2)
{
    int n    = (blockIdx.x * 256 + threadIdx.x) >> 6;
    int lane = threadIdx.x & 63;
    if (n >= NN) return;
    int p0 = rowptr[n], p1 = rowptr[n + 1];
    int h = lane >> 3, sub = lane & 7;

    float qf0[8], qf1[8], qf2[8], qf3[8];
    {
        const u16* qp = qW + (size_t)n * 2048 + h * 256 + sub * 8;
        s8v v0 = *(const s8v*)(qp + 0);
        s8v v1 = *(const s8v*)(qp + 64);
        s8v v2 = *(const s8v*)(qp + 128);
        s8v v3 = *(const s8v*)(qp + 192);
        #pragma unroll
        for (int q = 0; q < 8; ++q) {
            qf0[q] = b2f((u16)v0[q]); qf1[q] = b2f((u16)v1[q]);
            qf2[q] = b2f((u16)v2[q]); qf3[q] = b2f((u16)v3[q]);
        }
    }
    const float LSC = SCALEF * 1.44269504088896f;   // fold log2(e): exp2(a*log2e) == exp(a)
    float pr0 = prel[0 * NH + h] * LSC, pr1 = prel[1 * NH + h] * LSC;
    float pr2 = prel[2 * NH + h] * LSC, pr3 = prel[3 * NH + h] * LSC;

    float ssum = 0.f;
    float a0[8] = {}, a1[8] = {}, a2[8] = {}, a3[8] = {};

    // prefetch first edge's scalar chain
    int rN = 0, srcN = 0;
    if (p0 < p1) {
        int idx0 = erec[p0];
        rN = idx0 / EE;
        srcN = ei[idx0 + rN * EE];
    }

    for (int j = p0; j < p1; ++j) {
        int r = rN, src = srcN;           // wave-uniform r
        if (j + 1 < p1) {                 // prefetch next edge's index chain (scalars only)
            int idx2 = erec[j + 1];
            rN = idx2 / EE;
            srcN = ei[idx2 + rN * EE];
        }
        const u16* rowp = kqvb + (size_t)src * 1536;
        s8v kv = *(const s8v*)(rowp + h * 64 + sub * 8);        // k slice (head h)
        s8v vv = *(const s8v*)(rowp + 1024 + lane * 8);         // v slice (same head)
        float s = 0.f, pr;
        if (r == 0) {
            #pragma unroll
            for (int q = 0; q < 8; ++q) s += b2f((u16)kv[q]) * qf0[q];
            pr = pr0;
        } else if (r == 1) {
            #pragma unroll
            for (int q = 0; q < 8; ++q) s += b2f((u16)kv[q]) * qf1[q];
            pr = pr1;
        } else if (r == 2) {
            #pragma unroll
            for (int q = 0; q < 8; ++q) s += b2f((u16)kv[q]) * qf2[q];
            pr = pr2;
        } else {
            #pragma unroll
            for (int q = 0; q < 8; ++q) s += b2f((u16)kv[q]) * qf3[q];
            pr = pr3;
        }
        s += __shfl_xor(s, 1); s += __shfl_xor(s, 2); s += __shfl_xor(s, 4);
        float w = exp2f(s * pr);
        ssum += w;
        if (r == 0) {
            #pragma unroll
            for (int q = 0; q < 8; ++q) a0[q] += w * b2f((u16)vv[q]);
        } else if (r == 1) {
            #pragma unroll
            for (int q = 0; q < 8; ++q) a1[q] += w * b2f((u16)vv[q]);
        } else if (r == 2) {
            #pragma unroll
            for (int q = 0; q < 8; ++q) a2[q] += w * b2f((u16)vv[q]);
        } else {
            #pragma unroll
            for (int q = 0; q < 8; ++q) a3[q] += w * b2f((u16)vv[q]);
        }
    }

    float inv = 1.0f / (ssum + 1e-16f);
    u16* base = wsum2 + (size_t)n * 2048 + h * 256 + sub * 8;
    s8v o;
    #pragma unroll
    for (int q = 0; q < 8; ++q) o[q] = (short)f2b(a0[q] * inv);
    *(s8v*)(base + 0)   = o;
    #pragma unroll
    for (int q = 0; q < 8; ++q) o[q] = (short)f2b(a1[q] * inv);
    *(s8v*)(base + 64)  = o;
    #pragma unroll
    for (int q = 0; q < 8; ++q) o[q] = (short)f2b(a2[q] * inv);
    *(s8v*)(base + 128) = o;
    #pragma unroll
    for (int q = 0; q < 8; ++q) o[q] = (short)f2b(a3[q] * inv);
    *(s8v*)(base + 192) = o;
}

extern "C" void kernel_launch(void* const* d_in, const int* in_sizes, int n_in,
                              void* d_out, int out_size, void* d_ws, size_t ws_size,
                              hipStream_t stream)
{
    const float* x    = (const float*)d_in[0];
    const int*   ei   = (const int*)d_in[1];
    const float* ea   = (const float*)d_in[2];
    const float* Wkqv[2] = {(const float*)d_in[3],  (const float*)d_in[10]};
    const float* bkqv[2] = {(const float*)d_in[4],  (const float*)d_in[11]};
    const float* Wk[2]   = {(const float*)d_in[5],  (const float*)d_in[12]};
    const float* Wv[2]   = {(const float*)d_in[6],  (const float*)d_in[13]};
    const float* prel[2] = {(const float*)d_in[7],  (const float*)d_in[14]};
    const float* Wout[2] = {(const float*)d_in[8],  (const float*)d_in[15]};
    const float* bout[2] = {(const float*)d_in[9],  (const float*)d_in[16]};
    const float* skip1 = (const float*)d_in[17];
    const float* Wfc   = (const float*)d_in[18];
    const float* bfc   = (const float*)d_in[19];
    const float* We1   = (const float*)d_in[20];
    const float* be1   = (const float*)d_in[21];
    const float* We2   = (const float*)d_in[22];
    const float* be2   = (const float*)d_in[23];

    if (ws_size < WS_NEED) return;

    char* wsb = (char*)d_ws;
    u16*   kqvb  = (u16*)(wsb + B_KQV);
    u16*   qWbuf = (u16*)(wsb + B_KREL);     // qW; wsum2 overlays row-exclusively
    u16*   aggb  = (u16*)(wsb + B_AGG);
    u16*   h0b   = (u16*)(wsb + B_H0);
    u16*   h1b   = (u16*)(wsb + B_H1);
    int*   fillcnt = (int*)(wsb + B_LSE);    // build-time overlay
    int*   rowptr  = (int*)(wsb + B_ROWP);
    int*   erec    = (int*)(wsb + B_EREC);
    float* outf  = (float*)d_out;

    // bf16 weight arena
    u16* wt = (u16*)(wsb + B_WTS);
    u16* WkqvT[2] = {wt, wt + 393216};              wt += 393216 + 786432;
    u16* WkT2[2]  = {wt, wt + 131072};              wt += 262144;
    u16* WvT[2]   = {wt, wt + 131072};              wt += 262144;
    u16* WoutT[2] = {wt, wt + 262144};              wt += 524288;
    u16* WfcT     = wt;                             wt += 131072;
    u16* We1T     = wt;                             wt += 65536;
    u16* We2T     = wt;

    const dim3 blk(256);
    const int mt128  = (NN + 127) / 128;   // 157

    // ---- weight conversions ----
    transpose_f2b<<<dim3(CIN / 32, 1536 / 32), blk, 0, stream>>>(Wkqv[0], WkqvT[0], CIN, 1536);
    transpose_f2b<<<dim3(HIDW / 32, 1536 / 32), blk, 0, stream>>>(Wkqv[1], WkqvT[1], HIDW, 1536);
    transpose_f2b<<<dim3(HIDW / 32, HIDW / 32), blk, 0, stream>>>(Wout[0], WoutT[0], HIDW, HIDW);
    transpose_f2b<<<dim3(HIDW / 32, HIDW / 32), blk, 0, stream>>>(Wout[1], WoutT[1], HIDW, HIDW);
    transpose_f2b<<<dim3(HIDW / 32, OUTW / 32), blk, 0, stream>>>(Wfc, WfcT, HIDW, OUTW);
    transpose_f2b<<<dim3(CEDGE / 32, HIDW / 32), blk, 0, stream>>>(We1, We1T, CEDGE, HIDW);
    transpose_f2b<<<dim3(HIDW / 32, OUTW / 32), blk, 0, stream>>>(We2, We2T, HIDW, OUTW);
    for (int l = 0; l < 2; ++l) {
        conv_wk2<<<(131072 + 255) / 256, blk, 0, stream>>>(Wk[l], WkT2[l]);
        conv_wv<<<(131072 + 255) / 256, blk, 0, stream>>>(Wv[l], WvT[l]);
    }

    // ---- CSR build ----
    hipMemsetAsync(rowptr, 0, (NN + 1) * sizeof(int), stream);
    hipMemsetAsync(fillcnt, 0, NN * sizeof(int), stream);
    deg_kernel<<<(MEDGE + 255) / 256, blk, 0, stream>>>(ei, rowptr);
    scan_kernel<<<1, blk, 0, stream>>>(rowptr);
    fill_kernel<<<(MEDGE + 255) / 256, blk, 0, stream>>>(ei, rowptr, fillcnt, erec);

    for (int l = 0; l < 2; ++l) {
        int K = (l == 0) ? CIN : HIDW;

        // kqv = xin @ Wkqv + b  -> bf16 [20000 x 1536]
        if (l == 0)
            gemm_bf16<128, 0, true, true, false, true><<<dim3(12, mt128), blk, 0, stream>>>(
                (const void*)x, K, 0, WkqvT[0], K, 0, bkqv[0], kqvb, 1536, 0, NN, K, nullptr, nullptr);
        else
            gemm_bf16<128, 0, true, true, false><<<dim3(12, mt128), blk, 0, stream>>>(
                (const void*)h0b, K, 0, WkqvT[1], K, 0, bkqv[1], kqvb, 1536, 0, NN, K, nullptr, nullptr);

        // qW (all relations): per-head batched GEMM over q slice; out [n][h*256 + r*64 + d]
        gemm_bf16<128, 0, true, false, false><<<dim3(2, mt128, NH), blk, 0, stream>>>(
            (const void*)(kqvb + 512), 1536, 64, WkT2[l], 64, (size_t)256 * 64, nullptr,
            qWbuf, 2048, 256, NN, 64, nullptr, nullptr);

        // single-pass fused gather (wsum2 overlays qW row-exclusively)
        gather_attn<<<(NN * 64) / 256, blk, 0, stream>>>(
            kqvb, qWbuf, ei, rowptr, erec, prel[l], qWbuf);

        // agg = gelu( sum_r wsum_r @ Wv_r ) : per-head batched GEMM, K=256, N=64
        gemm_bf16<64, 2, true, false, false><<<dim3(1, mt128, NH), blk, 0, stream>>>(
            (const void*)qWbuf, 2048, 256, WvT[l], 256, (size_t)64 * 256, nullptr,
            aggb, 512, 64, NN, 256, nullptr, nullptr);

        // out = agg @ Wout + bout (+ skip mix on layer 1)
        if (l == 0)
            gemm_bf16<128, 0, true, true, false><<<dim3(4, mt128), blk, 0, stream>>>(
                (const void*)aggb, 512, 0, WoutT[0], 512, 0, bout[0], h0b, 512, 0, NN, 512, nullptr, nullptr);
        else
            gemm_bf16<128, 0, true, true, true><<<dim3(4, mt128), blk, 0, stream>>>(
                (const void*)aggb, 512, 0, WoutT[1], 512, 0, bout[1], h1b, 512, 0, NN, 512, h0b, skip1);
    }

    // node_embeds = h1 @ Wfc + bfc (f32 out)
    gemm_bf16<128, 0, false, true, false><<<dim3(2, mt128), blk, 0, stream>>>(
        (const void*)h1b, 512, 0, WfcT, 512, 0, bfc, outf, 256, 0, NN, 512, nullptr, nullptr);

    // edge_embeds = relu(ea @ We1 + be1) @ We2 + be2 — fused, 128-row / 8-wave blocks
    edge_mlp<<<MEDGE / 128, dim3(512), 0, stream>>>(ea, We1T, be1, We2T, be2, outf + 5120000);
}

// Round 17
// 710.605 us; speedup vs baseline: 1.3337x; 1.0339x over previous
//
#include <hip/hip_runtime.h>
#include <cstdint>
#include <cstddef>

#define NN      20000
#define RR      4
#define EE      40000
#define CIN     256
#define CEDGE   128
#define HIDW    512
#define OUTW    256
#define NH      8
#define MEDGE   (RR*EE)
#define SCALEF  0.125f

typedef unsigned short u16;
typedef short s8v  __attribute__((ext_vector_type(8)));
typedef float f32x4 __attribute__((ext_vector_type(4)));

// ---- ws layout (BYTE offsets) ----
#define B_KQV   10240000ull             // 20000*1536*2 = 61,440,000
#define B_KREL  71680000ull             // 20000*2048*2 = 81,920,000 (qW; wsum2 overlays row-exclusively)
#define B_AGG   153600000ull            // 20000*512*2
#define B_H0    174080000ull            // 20000*512*2
#define B_H1    194560000ull            // 20000*512*2
#define B_LSE   220160000ull            // fillcnt overlay during CSR build
#define B_ROWP  220800000ull            // 20001*4 -> pad
#define B_EREC  220880128ull            // 160000*4
#define B_WTS   221520128ull            // bf16 weights, ~5.2 MB
#define WS_NEED 227000000ull

__device__ __forceinline__ u16 f2b(float f) {
    unsigned u = __float_as_uint(f);
    unsigned r = (u + 0x7FFFu + ((u >> 16) & 1u)) >> 16;
    return (u16)r;
}
__device__ __forceinline__ float b2f(u16 h) { return __uint_as_float(((unsigned)h) << 16); }
__device__ __forceinline__ float gelu_exact(float x) {
    return 0.5f * x * (1.0f + erff(x * 0.70710678118654752f));
}

// async global->LDS, 16 bytes per lane; LDS dest must be wave-uniform base
__device__ __forceinline__ void gl_lds16(const u16* g, u16* l) {
    __builtin_amdgcn_global_load_lds(
        (const __attribute__((address_space(1))) void*)g,
        (__attribute__((address_space(3))) void*)l, 16, 0, 0);
}

// =============== generic bf16 MFMA GEMM (R6 single-buffered version, proven) ===============
template<int BN, int ACT, bool OUTBF16, bool BIAS, bool SKIP, bool AF32 = false>
__global__ __launch_bounds__(256) void gemm_bf16(
    const void* __restrict__ Av, int lda, size_t astride,
    const u16* __restrict__ BT, int ldb, size_t bstride,
    const float* __restrict__ bias,
    void* __restrict__ Cv, int ldc, size_t cstride,
    int M, int K,
    const u16* __restrict__ skipx, const float* __restrict__ gatep)
{
    constexpr int FN = BN / 32;
    constexpr int BI = BN / 32;
    __shared__ __align__(16) u16 As[128 * 64];
    __shared__ __align__(16) u16 Bs[BN * 64];

    const int t = threadIdx.x, lane = t & 63, wid = t >> 6;
    const int m0 = blockIdx.y * 128, n0 = blockIdx.x * BN;
    const int z  = blockIdx.z;
    const u16*   Bz = BT + (size_t)z * bstride;
    const float* Af = (const float*)Av + (AF32 ? (size_t)z * astride : 0);
    const u16*   Au = (const u16*)Av   + (AF32 ? 0 : (size_t)z * astride);
    const int wm = wid >> 1, wn = wid & 1;

    const int srow   = lane >> 3;
    const int schunk = (lane & 7) ^ srow;

    f32x4 acc[4][FN];
    #pragma unroll
    for (int i = 0; i < 4; ++i)
        #pragma unroll
        for (int j = 0; j < FN; ++j)
            acc[i][j] = (f32x4){0.f, 0.f, 0.f, 0.f};

    for (int k0 = 0; k0 < K; k0 += 64) {
        if (AF32) {
            #pragma unroll
            for (int i = 0; i < 4; ++i) {
                int c = i * 256 + t;
                int row = c >> 3, cc = c & 7;
                int gr = m0 + row; gr = gr < M ? gr : M - 1;
                const float* Ap = Af + (size_t)gr * lda + k0 + cc * 8;
                float4 p = *(const float4*)Ap;
                float4 q = *(const float4*)(Ap + 4);
                s8v v;
                v[0] = (short)f2b(p.x); v[1] = (short)f2b(p.y);
                v[2] = (short)f2b(p.z); v[3] = (short)f2b(p.w);
                v[4] = (short)f2b(q.x); v[5] = (short)f2b(q.y);
                v[6] = (short)f2b(q.z); v[7] = (short)f2b(q.w);
                *(s8v*)&As[row * 64 + ((cc ^ (row & 7)) << 3)] = v;
            }
        } else {
            #pragma unroll
            for (int i = 0; i < 4; ++i) {
                int t4 = wid * 4 + i;
                int row = t4 * 8 + srow;
                int gr = m0 + row; gr = gr < M ? gr : M - 1;
                gl_lds16(Au + (size_t)gr * lda + k0 + schunk * 8, &As[t4 * 512]);
            }
        }
        #pragma unroll
        for (int i = 0; i < BI; ++i) {
            int tb = wid * BI + i;
            int col = n0 + tb * 8 + srow;
            gl_lds16(Bz + (size_t)col * ldb + k0 + schunk * 8, &Bs[tb * 512]);
        }
        __syncthreads();
        #pragma unroll
        for (int ks = 0; ks < 2; ++ks) {
            s8v af[4], bf[FN];
            #pragma unroll
            for (int i = 0; i < 4; ++i) {
                int arow = wm * 64 + i * 16 + (lane & 15);
                int ac   = (ks * 4 + (lane >> 4)) ^ (lane & 7);
                af[i] = *(const s8v*)&As[arow * 64 + ac * 8];
            }
            #pragma unroll
            for (int j = 0; j < FN; ++j) {
                int brow = wn * (BN / 2) + j * 16 + (lane & 15);
                int bc   = (ks * 4 + (lane >> 4)) ^ (lane & 7);
                bf[j] = *(const s8v*)&Bs[brow * 64 + bc * 8];
            }
            #pragma unroll
            for (int i = 0; i < 4; ++i)
                #pragma unroll
                for (int j = 0; j < FN; ++j)
                    acc[i][j] = __builtin_amdgcn_mfma_f32_16x16x32_bf16(af[i], bf[j], acc[i][j], 0, 0, 0);
        }
        __syncthreads();
    }

    float gate = 1.f, ogate = 0.f;
    if (SKIP) { float s = *gatep; gate = 1.f / (1.f + expf(-s)); ogate = 1.f - gate; }
    u16*   Cb = (u16*)Cv   + (size_t)z * cstride;
    float* Cf = (float*)Cv + (size_t)z * cstride;
    #pragma unroll
    for (int i = 0; i < 4; ++i) {
        int rbase = m0 + wm * 64 + i * 16 + (lane >> 4) * 4;
        #pragma unroll
        for (int j = 0; j < FN; ++j) {
            int col = n0 + wn * (BN / 2) + j * 16 + (lane & 15);
            float bv = BIAS ? bias[col] : 0.f;
            #pragma unroll
            for (int q = 0; q < 4; ++q) {
                int r = rbase + q;
                if (r >= M) continue;
                float v = acc[i][j][q] + bv;
                if (ACT == 1) v = fmaxf(v, 0.f);
                if (ACT == 2) v = gelu_exact(v);
                if (SKIP) v = gate * v + ogate * b2f(skipx[(size_t)r * ldc + col]);
                if (OUTBF16) Cb[(size_t)r * ldc + col] = f2b(v);
                else         Cf[(size_t)r * ldc + col] = v;
            }
        }
    }
}

// =============== fused edge MLP v5 — 128 rows, 8 waves; transposed stage-1 output ===============
__global__ __launch_bounds__(512) void edge_mlp(
    const float* __restrict__ ea, const u16* __restrict__ We1T,
    const float* __restrict__ b1, const u16* __restrict__ We2T,
    const float* __restrict__ b2, float* __restrict__ out)
{
    __shared__ __align__(16) u16 Ae[128 * 128];
    __shared__ __align__(16) u16 Ic[128 * 128];

    const int t = threadIdx.x, lane = t & 63, w = t >> 6;   // w 0..7
    const int e0 = blockIdx.x * 128;
    const int l15 = lane & 15, l4 = lane >> 4;

    s8v w1f[4];
    auto loadW1 = [&](s8v* dst, int c) {
        #pragma unroll
        for (int ks = 0; ks < 4; ++ks) {
            int col1 = c * 128 + w * 16 + l15;
            dst[ks] = *(const s8v*)(We1T + (size_t)col1 * 128 + ks * 32 + l4 * 8);
        }
    };
    loadW1(w1f, 0);

    #pragma unroll
    for (int i = 0; i < 8; ++i) {
        int f   = i * 512 + t;
        int row = f >> 5;
        int c4  = f & 31;
        float4 p = *(const float4*)(ea + (size_t)(e0 + row) * 128 + c4 * 4);
        unsigned lo = (unsigned)f2b(p.x) | ((unsigned)f2b(p.y) << 16);
        unsigned hi = (unsigned)f2b(p.z) | ((unsigned)f2b(p.w) << 16);
        int chunk = c4 >> 1;
        int sub   = (c4 & 1) * 8;
        *(uint2*)((char*)Ae + row * 256 + ((chunk ^ (row & 7)) << 4) + sub)
            = make_uint2(lo, hi);
    }
    __syncthreads();

    f32x4 acc2[8][2];
    #pragma unroll
    for (int m = 0; m < 8; ++m) {
        acc2[m][0] = (f32x4){0.f, 0.f, 0.f, 0.f};
        acc2[m][1] = (f32x4){0.f, 0.f, 0.f, 0.f};
    }

    #pragma unroll
    for (int c = 0; c < 4; ++c) {
        f32x4 sacc[8];
        #pragma unroll
        for (int m = 0; m < 8; ++m) sacc[m] = (f32x4){0.f, 0.f, 0.f, 0.f};
        #pragma unroll
        for (int ks = 0; ks < 4; ++ks) {
            #pragma unroll
            for (int m = 0; m < 8; ++m) {
                int row = m * 16 + l15;
                int kc  = (ks * 4 + l4) ^ (row & 7);
                s8v af = *(const s8v*)&Ae[row * 128 + kc * 8];
                sacc[m] = __builtin_amdgcn_mfma_f32_16x16x32_bf16(w1f[ks], af, sacc[m], 0, 0, 0);
            }
        }
        s8v w2f[4][2];
        #pragma unroll
        for (int ks = 0; ks < 4; ++ks)
            #pragma unroll
            for (int n = 0; n < 2; ++n) {
                int col = w * 32 + n * 16 + l15;
                w2f[ks][n] = *(const s8v*)(We2T + (size_t)col * 512 + c * 128 + ks * 32 + l4 * 8);
            }
        __syncthreads();
        {
            const float4 bv4 = *(const float4*)(b1 + c * 128 + w * 16 + l4 * 4);
            int icol  = w * 16 + l4 * 4;
            int chunk = icol >> 3, sub = icol & 7;
            #pragma unroll
            for (int m = 0; m < 8; ++m) {
                int row = m * 16 + l15;
                u16 p0 = f2b(fmaxf(sacc[m][0] + bv4.x, 0.f));
                u16 p1 = f2b(fmaxf(sacc[m][1] + bv4.y, 0.f));
                u16 p2 = f2b(fmaxf(sacc[m][2] + bv4.z, 0.f));
                u16 p3 = f2b(fmaxf(sacc[m][3] + bv4.w, 0.f));
                unsigned lo = (unsigned)p0 | ((unsigned)p1 << 16);
                unsigned hi = (unsigned)p2 | ((unsigned)p3 << 16);
                *(uint2*)((char*)Ic + row * 256 + ((chunk ^ (row & 7)) << 4) + sub * 2)
                    = make_uint2(lo, hi);
            }
        }
        if (c < 3) loadW1(w1f, c + 1);
        __syncthreads();
        #pragma unroll
        for (int ks = 0; ks < 4; ++ks) {
            #pragma unroll
            for (int m = 0; m < 8; ++m) {
                int row = m * 16 + l15;
                int kc  = (ks * 4 + l4) ^ (row & 7);
                s8v af = *(const s8v*)&Ic[row * 128 + kc * 8];
                acc2[m][0] = __builtin_amdgcn_mfma_f32_16x16x32_bf16(af, w2f[ks][0], acc2[m][0], 0, 0, 0);
                acc2[m][1] = __builtin_amdgcn_mfma_f32_16x16x32_bf16(af, w2f[ks][1], acc2[m][1], 0, 0, 0);
            }
        }
    }

    #pragma unroll
    for (int n = 0; n < 2; ++n) {
        int col = w * 32 + n * 16 + l15;
        float bv = b2[col];
        #pragma unroll
        for (int m = 0; m < 8; ++m)
            #pragma unroll
            for (int q = 0; q < 4; ++q) {
                int row = m * 16 + l4 * 4 + q;
                out[(size_t)(e0 + row) * 256 + col] = acc2[m][n][q] + bv;
            }
    }
}

// =============== merged weight conversions: 11 launches -> 1 ===============
// Sections (block ranges) replicate the original kernels exactly.
__device__ __forceinline__ void do_transpose32(
    const float* __restrict__ W, u16* __restrict__ WT, int K, int N, int lb,
    float (*tile)[33])
{
    int bx = lb % (K / 32), by = lb / (K / 32);
    int kb = bx * 32, nb = by * 32;
    int tx = threadIdx.x & 31, ty = threadIdx.x >> 5;
    #pragma unroll
    for (int i = 0; i < 32; i += 8)
        tile[ty + i][tx] = W[(size_t)(kb + ty + i) * N + nb + tx];
    __syncthreads();
    #pragma unroll
    for (int i = 0; i < 32; i += 8)
        WT[(size_t)(nb + ty + i) * K + kb + tx] = f2b(tile[tx][ty + i]);
}

__global__ __launch_bounds__(256) void convert_all(
    const float* __restrict__ Wkqv0, const float* __restrict__ Wkqv1,
    const float* __restrict__ Wout0, const float* __restrict__ Wout1,
    const float* __restrict__ Wfc,   const float* __restrict__ We1,
    const float* __restrict__ We2,
    const float* __restrict__ Wk0,   const float* __restrict__ Wk1,
    const float* __restrict__ Wv0,   const float* __restrict__ Wv1,
    u16* __restrict__ WkqvT0, u16* __restrict__ WkqvT1,
    u16* __restrict__ WoutT0, u16* __restrict__ WoutT1,
    u16* __restrict__ WfcT,   u16* __restrict__ We1T, u16* __restrict__ We2T,
    u16* __restrict__ WkT20,  u16* __restrict__ WkT21,
    u16* __restrict__ WvT0,   u16* __restrict__ WvT1)
{
    __shared__ float tile[32][33];
    int b = blockIdx.x;
    if (b < 384) {                       // Wkqv0: 256x1536
        do_transpose32(Wkqv0, WkqvT0, 256, 1536, b, tile);
    } else if (b < 1152) {               // Wkqv1: 512x1536
        do_transpose32(Wkqv1, WkqvT1, 512, 1536, b - 384, tile);
    } else if (b < 1408) {               // Wout0: 512x512
        do_transpose32(Wout0, WoutT0, 512, 512, b - 1152, tile);
    } else if (b < 1664) {               // Wout1: 512x512
        do_transpose32(Wout1, WoutT1, 512, 512, b - 1408, tile);
    } else if (b < 1792) {               // Wfc: 512x256
        do_transpose32(Wfc, WfcT, 512, 256, b - 1664, tile);
    } else if (b < 1856) {               // We1: 128x512
        do_transpose32(We1, We1T, 128, 512, b - 1792, tile);
    } else if (b < 1984) {               // We2: 512x256
        do_transpose32(We2, We2T, 512, 256, b - 1856, tile);
    } else if (b < 3008) {               // conv_wk2 (Wk0 then Wk1)
        const float* Wk = (b < 2496) ? Wk0 : Wk1;
        u16* WkT2 = (b < 2496) ? WkT20 : WkT21;
        int lb = (b < 2496) ? (b - 1984) : (b - 2496);
        int idx = lb * 256 + threadIdx.x;
        if (idx < 8 * 256 * 64) {
            int e = idx & 63, rd = (idx >> 6) & 255, h = idx >> 14;
            int d = rd & 63, r = rd >> 6;
            WkT2[idx] = f2b(Wk[(size_t)(((r * 8 + h) * 64 + d) * 64) + e]);
        }
    } else {                             // conv_wv (Wv0 then Wv1)
        const float* Wv = (b < 3520) ? Wv0 : Wv1;
        u16* WvT = (b < 3520) ? WvT0 : WvT1;
        int lb = (b < 3520) ? (b - 3008) : (b - 3520);
        int idx = lb * 256 + threadIdx.x;
        if (idx < 8 * 64 * 256) {
            int d = idx & 63, r = (idx >> 6) & 3, e = (idx >> 8) & 63, h = idx >> 14;
            WvT[idx] = f2b(Wv[(size_t)(((r * 8 + h) * 64 + d) * 64) + e]);
        }
    }
}

// =============== CSR build (R11-exact) ===============
__global__ void deg_kernel(const int* __restrict__ ei, int* __restrict__ rowptr)
{
    int idx = blockIdx.x * 256 + threadIdx.x;
    if (idx >= MEDGE) return;
    int r = idx / EE;
    atomicAdd(&rowptr[ei[idx + (r + 1) * EE]], 1);
}

__global__ __launch_bounds__(256) void scan_kernel(int* __restrict__ rowptr)
{
    __shared__ int buf[256];
    __shared__ int carry;
    const int t = threadIdx.x;
    if (t == 0) carry = 0;
    __syncthreads();
    for (int base = 0; base < NN; base += 256) {
        int i = base + t;
        int v = (i < NN) ? rowptr[i] : 0;
        buf[t] = v;
        __syncthreads();
        for (int off = 1; off < 256; off <<= 1) {
            int tv = (t >= off) ? buf[t - off] : 0;
            __syncthreads();
            buf[t] += tv;
            __syncthreads();
        }
        int total = buf[255];
        int excl = buf[t] - v;
        int c = carry;
        __syncthreads();
        if (i < NN) rowptr[i] = c + excl;
        if (t == 0) carry = c + total;
        __syncthreads();
    }
    if (t == 0) rowptr[NN] = carry;
}

__global__ void fill_kernel(const int* __restrict__ ei, const int* __restrict__ rowptr,
                            int* __restrict__ fillcnt, int* __restrict__ erec)
{
    int idx = blockIdx.x * 256 + threadIdx.x;
    if (idx >= MEDGE) return;
    int r = idx / EE;
    int dst = ei[idx + (r + 1) * EE];
    int pos = rowptr[dst] + atomicAdd(&fillcnt[dst], 1);
    erec[pos] = idx;
}

// =============== single-pass fused gather v5: no-max softmax + scalar index prefetch ===============
__global__ __launch_bounds__(256) void gather_attn(
    const u16* __restrict__ kqvb, const u16* __restrict__ qW,
    const int* __restrict__ ei, const int* __restrict__ rowptr,
    const int* __restrict__ erec, const float* __restrict__ prel,
    u16* __restrict__ wsum2)
{
    int n    = (blockIdx.x * 256 + threadIdx.x) >> 6;
    int lane = threadIdx.x & 63;
    if (n >= NN) return;
    int p0 = rowptr[n], p1 = rowptr[n + 1];
    int h = lane >> 3, sub = lane & 7;

    float qf0[8], qf1[8], qf2[8], qf3[8];
    {
        const u16* qp = qW + (size_t)n * 2048 + h * 256 + sub * 8;
        s8v v0 = *(const s8v*)(qp + 0);
        s8v v1 = *(const s8v*)(qp + 64);
        s8v v2 = *(const s8v*)(qp + 128);
        s8v v3 = *(const s8v*)(qp + 192);
        #pragma unroll
        for (int q = 0; q < 8; ++q) {
            qf0[q] = b2f((u16)v0[q]); qf1[q] = b2f((u16)v1[q]);
            qf2[q] = b2f((u16)v2[q]); qf3[q] = b2f((u16)v3[q]);
        }
    }
    const float LSC = SCALEF * 1.44269504088896f;
    float pr0 = prel[0 * NH + h] * LSC, pr1 = prel[1 * NH + h] * LSC;
    float pr2 = prel[2 * NH + h] * LSC, pr3 = prel[3 * NH + h] * LSC;

    float ssum = 0.f;
    float a0[8] = {}, a1[8] = {}, a2[8] = {}, a3[8] = {};

    int rN = 0, srcN = 0;
    if (p0 < p1) {
        int idx0 = erec[p0];
        rN = idx0 / EE;
        srcN = ei[idx0 + rN * EE];
    }

    for (int j = p0; j < p1; ++j) {
        int r = rN, src = srcN;           // wave-uniform r
        if (j + 1 < p1) {
            int idx2 = erec[j + 1];
            rN = idx2 / EE;
            srcN = ei[idx2 + rN * EE];
        }
        const u16* rowp = kqvb + (size_t)src * 1536;
        s8v kv = *(const s8v*)(rowp + h * 64 + sub * 8);
        s8v vv = *(const s8v*)(rowp + 1024 + lane * 8);
        float s = 0.f, pr;
        if (r == 0) {
            #pragma unroll
            for (int q = 0; q < 8; ++q) s += b2f((u16)kv[q]) * qf0[q];
            pr = pr0;
        } else if (r == 1) {
            #pragma unroll
            for (int q = 0; q < 8; ++q) s += b2f((u16)kv[q]) * qf1[q];
            pr = pr1;
        } else if (r == 2) {
            #pragma unroll
            for (int q = 0; q < 8; ++q) s += b2f((u16)kv[q]) * qf2[q];
            pr = pr2;
        } else {
            #pragma unroll
            for (int q = 0; q < 8; ++q) s += b2f((u16)kv[q]) * qf3[q];
            pr = pr3;
        }
        s += __shfl_xor(s, 1); s += __shfl_xor(s, 2); s += __shfl_xor(s, 4);
        float w = exp2f(s * pr);
        ssum += w;
        if (r == 0) {
            #pragma unroll
            for (int q = 0; q < 8; ++q) a0[q] += w * b2f((u16)vv[q]);
        } else if (r == 1) {
            #pragma unroll
            for (int q = 0; q < 8; ++q) a1[q] += w * b2f((u16)vv[q]);
        } else if (r == 2) {
            #pragma unroll
            for (int q = 0; q < 8; ++q) a2[q] += w * b2f((u16)vv[q]);
        } else {
            #pragma unroll
            for (int q = 0; q < 8; ++q) a3[q] += w * b2f((u16)vv[q]);
        }
    }

    float inv = 1.0f / (ssum + 1e-16f);
    u16* base = wsum2 + (size_t)n * 2048 + h * 256 + sub * 8;
    s8v o;
    #pragma unroll
    for (int q = 0; q < 8; ++q) o[q] = (short)f2b(a0[q] * inv);
    *(s8v*)(base + 0)   = o;
    #pragma unroll
    for (int q = 0; q < 8; ++q) o[q] = (short)f2b(a1[q] * inv);
    *(s8v*)(base + 64)  = o;
    #pragma unroll
    for (int q = 0; q < 8; ++q) o[q] = (short)f2b(a2[q] * inv);
    *(s8v*)(base + 128) = o;
    #pragma unroll
    for (int q = 0; q < 8; ++q) o[q] = (short)f2b(a3[q] * inv);
    *(s8v*)(base + 192) = o;
}

extern "C" void kernel_launch(void* const* d_in, const int* in_sizes, int n_in,
                              void* d_out, int out_size, void* d_ws, size_t ws_size,
                              hipStream_t stream)
{
    const float* x    = (const float*)d_in[0];
    const int*   ei   = (const int*)d_in[1];
    const float* ea   = (const float*)d_in[2];
    const float* Wkqv[2] = {(const float*)d_in[3],  (const float*)d_in[10]};
    const float* bkqv[2] = {(const float*)d_in[4],  (const float*)d_in[11]};
    const float* Wk[2]   = {(const float*)d_in[5],  (const float*)d_in[12]};
    const float* Wv[2]   = {(const float*)d_in[6],  (const float*)d_in[13]};
    const float* prel[2] = {(const float*)d_in[7],  (const float*)d_in[14]};
    const float* Wout[2] = {(const float*)d_in[8],  (const float*)d_in[15]};
    const float* bout[2] = {(const float*)d_in[9],  (const float*)d_in[16]};
    const float* skip1 = (const float*)d_in[17];
    const float* Wfc   = (const float*)d_in[18];
    const float* bfc   = (const float*)d_in[19];
    const float* We1   = (const float*)d_in[20];
    const float* be1   = (const float*)d_in[21];
    const float* We2   = (const float*)d_in[22];
    const float* be2   = (const float*)d_in[23];

    if (ws_size < WS_NEED) return;

    char* wsb = (char*)d_ws;
    u16*   kqvb  = (u16*)(wsb + B_KQV);
    u16*   qWbuf = (u16*)(wsb + B_KREL);     // qW; wsum2 overlays row-exclusively
    u16*   aggb  = (u16*)(wsb + B_AGG);
    u16*   h0b   = (u16*)(wsb + B_H0);
    u16*   h1b   = (u16*)(wsb + B_H1);
    int*   fillcnt = (int*)(wsb + B_LSE);    // build-time overlay
    int*   rowptr  = (int*)(wsb + B_ROWP);
    int*   erec    = (int*)(wsb + B_EREC);
    float* outf  = (float*)d_out;

    // bf16 weight arena
    u16* wt = (u16*)(wsb + B_WTS);
    u16* WkqvT[2] = {wt, wt + 393216};              wt += 393216 + 786432;
    u16* WkT2[2]  = {wt, wt + 131072};              wt += 262144;
    u16* WvT[2]   = {wt, wt + 131072};              wt += 262144;
    u16* WoutT[2] = {wt, wt + 262144};              wt += 524288;
    u16* WfcT     = wt;                             wt += 131072;
    u16* We1T     = wt;                             wt += 65536;
    u16* We2T     = wt;

    const dim3 blk(256);
    const int mt128  = (NN + 127) / 128;   // 157

    // ---- all weight conversions in ONE kernel (was 11 launches) ----
    convert_all<<<4032, blk, 0, stream>>>(
        Wkqv[0], Wkqv[1], Wout[0], Wout[1], Wfc, We1, We2,
        Wk[0], Wk[1], Wv[0], Wv[1],
        WkqvT[0], WkqvT[1], WoutT[0], WoutT[1], WfcT, We1T, We2T,
        WkT2[0], WkT2[1], WvT[0], WvT[1]);

    // ---- CSR build ----
    hipMemsetAsync(rowptr, 0, (NN + 1) * sizeof(int), stream);
    hipMemsetAsync(fillcnt, 0, NN * sizeof(int), stream);
    deg_kernel<<<(MEDGE + 255) / 256, blk, 0, stream>>>(ei, rowptr);
    scan_kernel<<<1, blk, 0, stream>>>(rowptr);
    fill_kernel<<<(MEDGE + 255) / 256, blk, 0, stream>>>(ei, rowptr, fillcnt, erec);

    for (int l = 0; l < 2; ++l) {
        int K = (l == 0) ? CIN : HIDW;

        // kqv = xin @ Wkqv + b  -> bf16 [20000 x 1536]
        if (l == 0)
            gemm_bf16<128, 0, true, true, false, true><<<dim3(12, mt128), blk, 0, stream>>>(
                (const void*)x, K, 0, WkqvT[0], K, 0, bkqv[0], kqvb, 1536, 0, NN, K, nullptr, nullptr);
        else
            gemm_bf16<128, 0, true, true, false><<<dim3(12, mt128), blk, 0, stream>>>(
                (const void*)h0b, K, 0, WkqvT[1], K, 0, bkqv[1], kqvb, 1536, 0, NN, K, nullptr, nullptr);

        // qW (all relations): per-head batched GEMM over q slice; out [n][h*256 + r*64 + d]
        gemm_bf16<128, 0, true, false, false><<<dim3(2, mt128, NH), blk, 0, stream>>>(
            (const void*)(kqvb + 512), 1536, 64, WkT2[l], 64, (size_t)256 * 64, nullptr,
            qWbuf, 2048, 256, NN, 64, nullptr, nullptr);

        // single-pass fused gather (wsum2 overlays qW row-exclusively)
        gather_attn<<<(NN * 64) / 256, blk, 0, stream>>>(
            kqvb, qWbuf, ei, rowptr, erec, prel[l], qWbuf);

        // agg = gelu( sum_r wsum_r @ Wv_r ) : per-head batched GEMM, K=256, N=64
        gemm_bf16<64, 2, true, false, false><<<dim3(1, mt128, NH), blk, 0, stream>>>(
            (const void*)qWbuf, 2048, 256, WvT[l], 256, (size_t)64 * 256, nullptr,
            aggb, 512, 64, NN, 256, nullptr, nullptr);

        // out = agg @ Wout + bout (+ skip mix on layer 1)
        if (l == 0)
            gemm_bf16<128, 0, true, true, false><<<dim3(4, mt128), blk, 0, stream>>>(
                (const void*)aggb, 512, 0, WoutT[0], 512, 0, bout[0], h0b, 512, 0, NN, 512, nullptr, nullptr);
        else
            gemm_bf16<128, 0, true, true, true><<<dim3(4, mt128), blk, 0, stream>>>(
                (const void*)aggb, 512, 0, WoutT[1], 512, 0, bout[1], h1b, 512, 0, NN, 512, h0b, skip1);
    }

    // node_embeds = h1 @ Wfc + bfc (f32 out)
    gemm_bf16<128, 0, false, true, false><<<dim3(2, mt128), blk, 0, stream>>>(
        (const void*)h1b, 512, 0, WfcT, 512, 0, bfc, outf, 256, 0, NN, 512, nullptr, nullptr);

    // edge_embeds = relu(ea @ We1 + be1) @ We2 + be2 — fused, 128-row / 8-wave blocks
    edge_mlp<<<MEDGE / 128, dim3(512), 0, stream>>>(ea, We1T, be1, We2T, be2, outf + 5120000);
}

// Round 18
// 699.500 us; speedup vs baseline: 1.3548x; 1.0159x over previous
//
#include <hip/hip_runtime.h>
#include <cstdint>
#include <cstddef>

#define NN      20000
#define RR      4
#define EE      40000
#define CIN     256
#define CEDGE   128
#define HIDW    512
#define OUTW    256
#define NH      8
#define MEDGE   (RR*EE)
#define SCALEF  0.125f

typedef unsigned short u16;
typedef short s8v  __attribute__((ext_vector_type(8)));
typedef float f32x4 __attribute__((ext_vector_type(4)));

// ---- ws layout (BYTE offsets) ----
#define B_KQV   10240000ull             // 20000*1536*2 = 61,440,000
#define B_KREL  71680000ull             // 20000*2048*2 = 81,920,000 (qW; wsum2 overlays row-exclusively)
#define B_AGG   153600000ull            // 20000*512*2
#define B_H0    174080000ull            // 20000*512*2
#define B_H1    194560000ull            // 20000*512*2
#define B_LSE   220160000ull            // fillcnt overlay during CSR build
#define B_ROWP  220800000ull            // 20001*4 -> pad
#define B_EREC  220880128ull            // 160000*4
#define B_WTS   221520128ull            // bf16 weights, ~5.2 MB
#define WS_NEED 227000000ull

__device__ __forceinline__ u16 f2b(float f) {
    unsigned u = __float_as_uint(f);
    unsigned r = (u + 0x7FFFu + ((u >> 16) & 1u)) >> 16;
    return (u16)r;
}
__device__ __forceinline__ float b2f(u16 h) { return __uint_as_float(((unsigned)h) << 16); }
__device__ __forceinline__ float gelu_exact(float x) {
    return 0.5f * x * (1.0f + erff(x * 0.70710678118654752f));
}

// async global->LDS, 16 bytes per lane; LDS dest must be wave-uniform base
__device__ __forceinline__ void gl_lds16(const u16* g, u16* l) {
    __builtin_amdgcn_global_load_lds(
        (const __attribute__((address_space(1))) void*)g,
        (__attribute__((address_space(3))) void*)l, 16, 0, 0);
}

// =============== generic bf16 MFMA GEMM (R6 single-buffered version, proven) ===============
template<int BN, int ACT, bool OUTBF16, bool BIAS, bool SKIP, bool AF32 = false>
__global__ __launch_bounds__(256) void gemm_bf16(
    const void* __restrict__ Av, int lda, size_t astride,
    const u16* __restrict__ BT, int ldb, size_t bstride,
    const float* __restrict__ bias,
    void* __restrict__ Cv, int ldc, size_t cstride,
    int M, int K,
    const u16* __restrict__ skipx, const float* __restrict__ gatep)
{
    constexpr int FN = BN / 32;
    constexpr int BI = BN / 32;
    __shared__ __align__(16) u16 As[128 * 64];
    __shared__ __align__(16) u16 Bs[BN * 64];

    const int t = threadIdx.x, lane = t & 63, wid = t >> 6;
    const int m0 = blockIdx.y * 128, n0 = blockIdx.x * BN;
    const int z  = blockIdx.z;
    const u16*   Bz = BT + (size_t)z * bstride;
    const float* Af = (const float*)Av + (AF32 ? (size_t)z * astride : 0);
    const u16*   Au = (const u16*)Av   + (AF32 ? 0 : (size_t)z * astride);
    const int wm = wid >> 1, wn = wid & 1;

    const int srow   = lane >> 3;
    const int schunk = (lane & 7) ^ srow;

    f32x4 acc[4][FN];
    #pragma unroll
    for (int i = 0; i < 4; ++i)
        #pragma unroll
        for (int j = 0; j < FN; ++j)
            acc[i][j] = (f32x4){0.f, 0.f, 0.f, 0.f};

    for (int k0 = 0; k0 < K; k0 += 64) {
        if (AF32) {
            #pragma unroll
            for (int i = 0; i < 4; ++i) {
                int c = i * 256 + t;
                int row = c >> 3, cc = c & 7;
                int gr = m0 + row; gr = gr < M ? gr : M - 1;
                const float* Ap = Af + (size_t)gr * lda + k0 + cc * 8;
                float4 p = *(const float4*)Ap;
                float4 q = *(const float4*)(Ap + 4);
                s8v v;
                v[0] = (short)f2b(p.x); v[1] = (short)f2b(p.y);
                v[2] = (short)f2b(p.z); v[3] = (short)f2b(p.w);
                v[4] = (short)f2b(q.x); v[5] = (short)f2b(q.y);
                v[6] = (short)f2b(q.z); v[7] = (short)f2b(q.w);
                *(s8v*)&As[row * 64 + ((cc ^ (row & 7)) << 3)] = v;
            }
        } else {
            #pragma unroll
            for (int i = 0; i < 4; ++i) {
                int t4 = wid * 4 + i;
                int row = t4 * 8 + srow;
                int gr = m0 + row; gr = gr < M ? gr : M - 1;
                gl_lds16(Au + (size_t)gr * lda + k0 + schunk * 8, &As[t4 * 512]);
            }
        }
        #pragma unroll
        for (int i = 0; i < BI; ++i) {
            int tb = wid * BI + i;
            int col = n0 + tb * 8 + srow;
            gl_lds16(Bz + (size_t)col * ldb + k0 + schunk * 8, &Bs[tb * 512]);
        }
        __syncthreads();
        #pragma unroll
        for (int ks = 0; ks < 2; ++ks) {
            s8v af[4], bf[FN];
            #pragma unroll
            for (int i = 0; i < 4; ++i) {
                int arow = wm * 64 + i * 16 + (lane & 15);
                int ac   = (ks * 4 + (lane >> 4)) ^ (lane & 7);
                af[i] = *(const s8v*)&As[arow * 64 + ac * 8];
            }
            #pragma unroll
            for (int j = 0; j < FN; ++j) {
                int brow = wn * (BN / 2) + j * 16 + (lane & 15);
                int bc   = (ks * 4 + (lane >> 4)) ^ (lane & 7);
                bf[j] = *(const s8v*)&Bs[brow * 64 + bc * 8];
            }
            #pragma unroll
            for (int i = 0; i < 4; ++i)
                #pragma unroll
                for (int j = 0; j < FN; ++j)
                    acc[i][j] = __builtin_amdgcn_mfma_f32_16x16x32_bf16(af[i], bf[j], acc[i][j], 0, 0, 0);
        }
        __syncthreads();
    }

    float gate = 1.f, ogate = 0.f;
    if (SKIP) { float s = *gatep; gate = 1.f / (1.f + expf(-s)); ogate = 1.f - gate; }
    u16*   Cb = (u16*)Cv   + (size_t)z * cstride;
    float* Cf = (float*)Cv + (size_t)z * cstride;
    #pragma unroll
    for (int i = 0; i < 4; ++i) {
        int rbase = m0 + wm * 64 + i * 16 + (lane >> 4) * 4;
        #pragma unroll
        for (int j = 0; j < FN; ++j) {
            int col = n0 + wn * (BN / 2) + j * 16 + (lane & 15);
            float bv = BIAS ? bias[col] : 0.f;
            #pragma unroll
            for (int q = 0; q < 4; ++q) {
                int r = rbase + q;
                if (r >= M) continue;
                float v = acc[i][j][q] + bv;
                if (ACT == 1) v = fmaxf(v, 0.f);
                if (ACT == 2) v = gelu_exact(v);
                if (SKIP) v = gate * v + ogate * b2f(skipx[(size_t)r * ldc + col]);
                if (OUTBF16) Cb[(size_t)r * ldc + col] = f2b(v);
                else         Cf[(size_t)r * ldc + col] = v;
            }
        }
    }
}

// =============== fused edge MLP v6 — 64 rows, 8 waves, HALVED footprint for 2x occupancy ===============
// Same barrier schedule as proven v5; tile halved: LDS 64->32 KiB, acc VGPRs halved.
// Stage 1 (transposed): wave owns 16 interm cols over 64 rows; stage 2: 32 out cols.
__global__ __launch_bounds__(512) void edge_mlp(
    const float* __restrict__ ea, const u16* __restrict__ We1T,
    const float* __restrict__ b1, const u16* __restrict__ We2T,
    const float* __restrict__ b2, float* __restrict__ out)
{
    __shared__ __align__(16) u16 Ae[64 * 128];
    __shared__ __align__(16) u16 Ic[64 * 128];

    const int t = threadIdx.x, lane = t & 63, w = t >> 6;   // w 0..7
    const int e0 = blockIdx.x * 64;
    const int l15 = lane & 15, l4 = lane >> 4;

    s8v w1f[4];
    auto loadW1 = [&](s8v* dst, int c) {
        #pragma unroll
        for (int ks = 0; ks < 4; ++ks) {
            int col1 = c * 128 + w * 16 + l15;
            dst[ks] = *(const s8v*)(We1T + (size_t)col1 * 128 + ks * 32 + l4 * 8);
        }
    };
    loadW1(w1f, 0);

    // stage ea tile: 64 rows x 128 f32 -> bf16, chunk-XOR swizzle (2048 float4s)
    #pragma unroll
    for (int i = 0; i < 4; ++i) {
        int f   = i * 512 + t;
        int row = f >> 5;               // 0..63
        int c4  = f & 31;
        float4 p = *(const float4*)(ea + (size_t)(e0 + row) * 128 + c4 * 4);
        unsigned lo = (unsigned)f2b(p.x) | ((unsigned)f2b(p.y) << 16);
        unsigned hi = (unsigned)f2b(p.z) | ((unsigned)f2b(p.w) << 16);
        int chunk = c4 >> 1;
        int sub   = (c4 & 1) * 8;
        *(uint2*)((char*)Ae + row * 256 + ((chunk ^ (row & 7)) << 4) + sub)
            = make_uint2(lo, hi);
    }
    __syncthreads();

    f32x4 acc2[4][2];
    #pragma unroll
    for (int m = 0; m < 4; ++m) {
        acc2[m][0] = (f32x4){0.f, 0.f, 0.f, 0.f};
        acc2[m][1] = (f32x4){0.f, 0.f, 0.f, 0.f};
    }

    #pragma unroll
    for (int c = 0; c < 4; ++c) {
        // ---- stage 1 (transposed): lane holds 4 consecutive icols of one erow ----
        f32x4 sacc[4];
        #pragma unroll
        for (int m = 0; m < 4; ++m) sacc[m] = (f32x4){0.f, 0.f, 0.f, 0.f};
        #pragma unroll
        for (int ks = 0; ks < 4; ++ks) {
            #pragma unroll
            for (int m = 0; m < 4; ++m) {
                int row = m * 16 + l15;
                int kc  = (ks * 4 + l4) ^ (row & 7);
                s8v af = *(const s8v*)&Ae[row * 128 + kc * 8];
                sacc[m] = __builtin_amdgcn_mfma_f32_16x16x32_bf16(w1f[ks], af, sacc[m], 0, 0, 0);
            }
        }
        s8v w2f[4][2];
        #pragma unroll
        for (int ks = 0; ks < 4; ++ks)
            #pragma unroll
            for (int n = 0; n < 2; ++n) {
                int col = w * 32 + n * 16 + l15;
                w2f[ks][n] = *(const s8v*)(We2T + (size_t)col * 512 + c * 128 + ks * 32 + l4 * 8);
            }
        __syncthreads();
        // write interm (bias+relu): each lane packs 4 consecutive cols -> one 8B write per m
        {
            const float4 bv4 = *(const float4*)(b1 + c * 128 + w * 16 + l4 * 4);
            int icol  = w * 16 + l4 * 4;
            int chunk = icol >> 3, sub = icol & 7;
            #pragma unroll
            for (int m = 0; m < 4; ++m) {
                int row = m * 16 + l15;
                u16 p0 = f2b(fmaxf(sacc[m][0] + bv4.x, 0.f));
                u16 p1 = f2b(fmaxf(sacc[m][1] + bv4.y, 0.f));
                u16 p2 = f2b(fmaxf(sacc[m][2] + bv4.z, 0.f));
                u16 p3 = f2b(fmaxf(sacc[m][3] + bv4.w, 0.f));
                unsigned lo = (unsigned)p0 | ((unsigned)p1 << 16);
                unsigned hi = (unsigned)p2 | ((unsigned)p3 << 16);
                *(uint2*)((char*)Ic + row * 256 + ((chunk ^ (row & 7)) << 4) + sub * 2)
                    = make_uint2(lo, hi);
            }
        }
        if (c < 3) loadW1(w1f, c + 1);
        __syncthreads();
        // ---- stage 2: out cols [w*32, w*32+32), accumulate over this K-chunk ----
        #pragma unroll
        for (int ks = 0; ks < 4; ++ks) {
            #pragma unroll
            for (int m = 0; m < 4; ++m) {
                int row = m * 16 + l15;
                int kc  = (ks * 4 + l4) ^ (row & 7);
                s8v af = *(const s8v*)&Ic[row * 128 + kc * 8];
                acc2[m][0] = __builtin_amdgcn_mfma_f32_16x16x32_bf16(af, w2f[ks][0], acc2[m][0], 0, 0, 0);
                acc2[m][1] = __builtin_amdgcn_mfma_f32_16x16x32_bf16(af, w2f[ks][1], acc2[m][1], 0, 0, 0);
            }
        }
    }

    #pragma unroll
    for (int n = 0; n < 2; ++n) {
        int col = w * 32 + n * 16 + l15;
        float bv = b2[col];
        #pragma unroll
        for (int m = 0; m < 4; ++m)
            #pragma unroll
            for (int q = 0; q < 4; ++q) {
                int row = m * 16 + l4 * 4 + q;
                out[(size_t)(e0 + row) * 256 + col] = acc2[m][n][q] + bv;
            }
    }
}

// =============== merged weight conversions + CSR zeroing: 13 launches -> 1 ===============
__device__ __forceinline__ void do_transpose32(
    const float* __restrict__ W, u16* __restrict__ WT, int K, int N, int lb,
    float (*tile)[33])
{
    int bx = lb % (K / 32), by = lb / (K / 32);
    int kb = bx * 32, nb = by * 32;
    int tx = threadIdx.x & 31, ty = threadIdx.x >> 5;
    #pragma unroll
    for (int i = 0; i < 32; i += 8)
        tile[ty + i][tx] = W[(size_t)(kb + ty + i) * N + nb + tx];
    __syncthreads();
    #pragma unroll
    for (int i = 0; i < 32; i += 8)
        WT[(size_t)(nb + ty + i) * K + kb + tx] = f2b(tile[tx][ty + i]);
}

__global__ __launch_bounds__(256) void convert_all(
    const float* __restrict__ Wkqv0, const float* __restrict__ Wkqv1,
    const float* __restrict__ Wout0, const float* __restrict__ Wout1,
    const float* __restrict__ Wfc,   const float* __restrict__ We1,
    const float* __restrict__ We2,
    const float* __restrict__ Wk0,   const float* __restrict__ Wk1,
    const float* __restrict__ Wv0,   const float* __restrict__ Wv1,
    u16* __restrict__ WkqvT0, u16* __restrict__ WkqvT1,
    u16* __restrict__ WoutT0, u16* __restrict__ WoutT1,
    u16* __restrict__ WfcT,   u16* __restrict__ We1T, u16* __restrict__ We2T,
    u16* __restrict__ WkT20,  u16* __restrict__ WkT21,
    u16* __restrict__ WvT0,   u16* __restrict__ WvT1,
    int* __restrict__ rowptr, int* __restrict__ fillcnt)
{
    __shared__ float tile[32][33];
    int b = blockIdx.x;
    if (b < 384) {                       // Wkqv0: 256x1536
        do_transpose32(Wkqv0, WkqvT0, 256, 1536, b, tile);
    } else if (b < 1152) {               // Wkqv1: 512x1536
        do_transpose32(Wkqv1, WkqvT1, 512, 1536, b - 384, tile);
    } else if (b < 1408) {               // Wout0: 512x512
        do_transpose32(Wout0, WoutT0, 512, 512, b - 1152, tile);
    } else if (b < 1664) {               // Wout1: 512x512
        do_transpose32(Wout1, WoutT1, 512, 512, b - 1408, tile);
    } else if (b < 1792) {               // Wfc: 512x256
        do_transpose32(Wfc, WfcT, 512, 256, b - 1664, tile);
    } else if (b < 1856) {               // We1: 128x512
        do_transpose32(We1, We1T, 128, 512, b - 1792, tile);
    } else if (b < 1984) {               // We2: 512x256
        do_transpose32(We2, We2T, 512, 256, b - 1856, tile);
    } else if (b < 3008) {               // conv_wk2 (Wk0 then Wk1)
        const float* Wk = (b < 2496) ? Wk0 : Wk1;
        u16* WkT2 = (b < 2496) ? WkT20 : WkT21;
        int lb = (b < 2496) ? (b - 1984) : (b - 2496);
        int idx = lb * 256 + threadIdx.x;
        if (idx < 8 * 256 * 64) {
            int e = idx & 63, rd = (idx >> 6) & 255, h = idx >> 14;
            int d = rd & 63, r = rd >> 6;
            WkT2[idx] = f2b(Wk[(size_t)(((r * 8 + h) * 64 + d) * 64) + e]);
        }
    } else if (b < 4032) {               // conv_wv (Wv0 then Wv1)
        const float* Wv = (b < 3520) ? Wv0 : Wv1;
        u16* WvT = (b < 3520) ? WvT0 : WvT1;
        int lb = (b < 3520) ? (b - 3008) : (b - 3520);
        int idx = lb * 256 + threadIdx.x;
        if (idx < 8 * 64 * 256) {
            int d = idx & 63, r = (idx >> 6) & 3, e = (idx >> 8) & 63, h = idx >> 14;
            WvT[idx] = f2b(Wv[(size_t)(((r * 8 + h) * 64 + d) * 64) + e]);
        }
    } else if (b < 4111) {               // zero rowptr (20001 ints)
        int idx = (b - 4032) * 256 + threadIdx.x;
        if (idx < NN + 1) rowptr[idx] = 0;
    } else {                             // zero fillcnt (20000 ints)
        int idx = (b - 4111) * 256 + threadIdx.x;
        if (idx < NN) fillcnt[idx] = 0;
    }
}

// =============== CSR build (R11-exact) ===============
__global__ void deg_kernel(const int* __restrict__ ei, int* __restrict__ rowptr)
{
    int idx = blockIdx.x * 256 + threadIdx.x;
    if (idx >= MEDGE) return;
    int r = idx / EE;
    atomicAdd(&rowptr[ei[idx + (r + 1) * EE]], 1);
}

__global__ __launch_bounds__(256) void scan_kernel(int* __restrict__ rowptr)
{
    __shared__ int buf[256];
    __shared__ int carry;
    const int t = threadIdx.x;
    if (t == 0) carry = 0;
    __syncthreads();
    for (int base = 0; base < NN; base += 256) {
        int i = base + t;
        int v = (i < NN) ? rowptr[i] : 0;
        buf[t] = v;
        __syncthreads();
        for (int off = 1; off < 256; off <<= 1) {
            int tv = (t >= off) ? buf[t - off] : 0;
            __syncthreads();
            buf[t] += tv;
            __syncthreads();
        }
        int total = buf[255];
        int excl = buf[t] - v;
        int c = carry;
        __syncthreads();
        if (i < NN) rowptr[i] = c + excl;
        if (t == 0) carry = c + total;
        __syncthreads();
    }
    if (t == 0) rowptr[NN] = carry;
}

__global__ void fill_kernel(const int* __restrict__ ei, const int* __restrict__ rowptr,
                            int* __restrict__ fillcnt, int* __restrict__ erec)
{
    int idx = blockIdx.x * 256 + threadIdx.x;
    if (idx >= MEDGE) return;
    int r = idx / EE;
    int dst = ei[idx + (r + 1) * EE];
    int pos = rowptr[dst] + atomicAdd(&fillcnt[dst], 1);
    erec[pos] = idx;
}

// =============== single-pass fused gather v5: no-max softmax + scalar index prefetch ===============
__global__ __launch_bounds__(256) void gather_attn(
    const u16* __restrict__ kqvb, const u16* __restrict__ qW,
    const int* __restrict__ ei, const int* __restrict__ rowptr,
    const int* __restrict__ erec, const float* __restrict__ prel,
    u16* __restrict__ wsum2)
{
    int n    = (blockIdx.x * 256 + threadIdx.x) >> 6;
    int lane = threadIdx.x & 63;
    if (n >= NN) return;
    int p0 = rowptr[n], p1 = rowptr[n + 1];
    int h = lane >> 3, sub = lane & 7;

    float qf0[8], qf1[8], qf2[8], qf3[8];
    {
        const u16* qp = qW + (size_t)n * 2048 + h * 256 + sub * 8;
        s8v v0 = *(const s8v*)(qp + 0);
        s8v v1 = *(const s8v*)(qp + 64);
        s8v v2 = *(const s8v*)(qp + 128);
        s8v v3 = *(const s8v*)(qp + 192);
        #pragma unroll
        for (int q = 0; q < 8; ++q) {
            qf0[q] = b2f((u16)v0[q]); qf1[q] = b2f((u16)v1[q]);
            qf2[q] = b2f((u16)v2[q]); qf3[q] = b2f((u16)v3[q]);
        }
    }
    const float LSC = SCALEF * 1.44269504088896f;
    float pr0 = prel[0 * NH + h] * LSC, pr1 = prel[1 * NH + h] * LSC;
    float pr2 = prel[2 * NH + h] * LSC, pr3 = prel[3 * NH + h] * LSC;

    float ssum = 0.f;
    float a0[8] = {}, a1[8] = {}, a2[8] = {}, a3[8] = {};

    int rN = 0, srcN = 0;
    if (p0 < p1) {
        int idx0 = erec[p0];
        rN = idx0 / EE;
        srcN = ei[idx0 + rN * EE];
    }

    for (int j = p0; j < p1; ++j) {
        int r = rN, src = srcN;           // wave-uniform r
        if (j + 1 < p1) {
            int idx2 = erec[j + 1];
            rN = idx2 / EE;
            srcN = ei[idx2 + rN * EE];
        }
        const u16* rowp = kqvb + (size_t)src * 1536;
        s8v kv = *(const s8v*)(rowp + h * 64 + sub * 8);
        s8v vv = *(const s8v*)(rowp + 1024 + lane * 8);
        float s = 0.f, pr;
        if (r == 0) {
            #pragma unroll
            for (int q = 0; q < 8; ++q) s += b2f((u16)kv[q]) * qf0[q];
            pr = pr0;
        } else if (r == 1) {
            #pragma unroll
            for (int q = 0; q < 8; ++q) s += b2f((u16)kv[q]) * qf1[q];
            pr = pr1;
        } else if (r == 2) {
            #pragma unroll
            for (int q = 0; q < 8; ++q) s += b2f((u16)kv[q]) * qf2[q];
            pr = pr2;
        } else {
            #pragma unroll
            for (int q = 0; q < 8; ++q) s += b2f((u16)kv[q]) * qf3[q];
            pr = pr3;
        }
        s += __shfl_xor(s, 1); s += __shfl_xor(s, 2); s += __shfl_xor(s, 4);
        float w = exp2f(s * pr);
        ssum += w;
        if (r == 0) {
            #pragma unroll
            for (int q = 0; q < 8; ++q) a0[q] += w * b2f((u16)vv[q]);
        } else if (r == 1) {
            #pragma unroll
            for (int q = 0; q < 8; ++q) a1[q] += w * b2f((u16)vv[q]);
        } else if (r == 2) {
            #pragma unroll
            for (int q = 0; q < 8; ++q) a2[q] += w * b2f((u16)vv[q]);
        } else {
            #pragma unroll
            for (int q = 0; q < 8; ++q) a3[q] += w * b2f((u16)vv[q]);
        }
    }

    float inv = 1.0f / (ssum + 1e-16f);
    u16* base = wsum2 + (size_t)n * 2048 + h * 256 + sub * 8;
    s8v o;
    #pragma unroll
    for (int q = 0; q < 8; ++q) o[q] = (short)f2b(a0[q] * inv);
    *(s8v*)(base + 0)   = o;
    #pragma unroll
    for (int q = 0; q < 8; ++q) o[q] = (short)f2b(a1[q] * inv);
    *(s8v*)(base + 64)  = o;
    #pragma unroll
    for (int q = 0; q < 8; ++q) o[q] = (short)f2b(a2[q] * inv);
    *(s8v*)(base + 128) = o;
    #pragma unroll
    for (int q = 0; q < 8; ++q) o[q] = (short)f2b(a3[q] * inv);
    *(s8v*)(base + 192) = o;
}

extern "C" void kernel_launch(void* const* d_in, const int* in_sizes, int n_in,
                              void* d_out, int out_size, void* d_ws, size_t ws_size,
                              hipStream_t stream)
{
    const float* x    = (const float*)d_in[0];
    const int*   ei   = (const int*)d_in[1];
    const float* ea   = (const float*)d_in[2];
    const float* Wkqv[2] = {(const float*)d_in[3],  (const float*)d_in[10]};
    const float* bkqv[2] = {(const float*)d_in[4],  (const float*)d_in[11]};
    const float* Wk[2]   = {(const float*)d_in[5],  (const float*)d_in[12]};
    const float* Wv[2]   = {(const float*)d_in[6],  (const float*)d_in[13]};
    const float* prel[2] = {(const float*)d_in[7],  (const float*)d_in[14]};
    const float* Wout[2] = {(const float*)d_in[8],  (const float*)d_in[15]};
    const float* bout[2] = {(const float*)d_in[9],  (const float*)d_in[16]};
    const float* skip1 = (const float*)d_in[17];
    const float* Wfc   = (const float*)d_in[18];
    const float* bfc   = (const float*)d_in[19];
    const float* We1   = (const float*)d_in[20];
    const float* be1   = (const float*)d_in[21];
    const float* We2   = (const float*)d_in[22];
    const float* be2   = (const float*)d_in[23];

    if (ws_size < WS_NEED) return;

    char* wsb = (char*)d_ws;
    u16*   kqvb  = (u16*)(wsb + B_KQV);
    u16*   qWbuf = (u16*)(wsb + B_KREL);     // qW; wsum2 overlays row-exclusively
    u16*   aggb  = (u16*)(wsb + B_AGG);
    u16*   h0b   = (u16*)(wsb + B_H0);
    u16*   h1b   = (u16*)(wsb + B_H1);
    int*   fillcnt = (int*)(wsb + B_LSE);    // build-time overlay
    int*   rowptr  = (int*)(wsb + B_ROWP);
    int*   erec    = (int*)(wsb + B_EREC);
    float* outf  = (float*)d_out;

    // bf16 weight arena
    u16* wt = (u16*)(wsb + B_WTS);
    u16* WkqvT[2] = {wt, wt + 393216};              wt += 393216 + 786432;
    u16* WkT2[2]  = {wt, wt + 131072};              wt += 262144;
    u16* WvT[2]   = {wt, wt + 131072};              wt += 262144;
    u16* WoutT[2] = {wt, wt + 262144};              wt += 524288;
    u16* WfcT     = wt;                             wt += 131072;
    u16* We1T     = wt;                             wt += 65536;
    u16* We2T     = wt;

    const dim3 blk(256);
    const int mt128  = (NN + 127) / 128;   // 157

    // ---- all weight conversions + CSR zeroing in ONE kernel ----
    convert_all<<<4190, blk, 0, stream>>>(
        Wkqv[0], Wkqv[1], Wout[0], Wout[1], Wfc, We1, We2,
        Wk[0], Wk[1], Wv[0], Wv[1],
        WkqvT[0], WkqvT[1], WoutT[0], WoutT[1], WfcT, We1T, We2T,
        WkT2[0], WkT2[1], WvT[0], WvT[1],
        rowptr, fillcnt);

    // ---- CSR build ----
    deg_kernel<<<(MEDGE + 255) / 256, blk, 0, stream>>>(ei, rowptr);
    scan_kernel<<<1, blk, 0, stream>>>(rowptr);
    fill_kernel<<<(MEDGE + 255) / 256, blk, 0, stream>>>(ei, rowptr, fillcnt, erec);

    for (int l = 0; l < 2; ++l) {
        int K = (l == 0) ? CIN : HIDW;

        // kqv = xin @ Wkqv + b  -> bf16 [20000 x 1536]
        if (l == 0)
            gemm_bf16<128, 0, true, true, false, true><<<dim3(12, mt128), blk, 0, stream>>>(
                (const void*)x, K, 0, WkqvT[0], K, 0, bkqv[0], kqvb, 1536, 0, NN, K, nullptr, nullptr);
        else
            gemm_bf16<128, 0, true, true, false><<<dim3(12, mt128), blk, 0, stream>>>(
                (const void*)h0b, K, 0, WkqvT[1], K, 0, bkqv[1], kqvb, 1536, 0, NN, K, nullptr, nullptr);

        // qW (all relations): per-head batched GEMM over q slice; out [n][h*256 + r*64 + d]
        gemm_bf16<128, 0, true, false, false><<<dim3(2, mt128, NH), blk, 0, stream>>>(
            (const void*)(kqvb + 512), 1536, 64, WkT2[l], 64, (size_t)256 * 64, nullptr,
            qWbuf, 2048, 256, NN, 64, nullptr, nullptr);

        // single-pass fused gather (wsum2 overlays qW row-exclusively)
        gather_attn<<<(NN * 64) / 256, blk, 0, stream>>>(
            kqvb, qWbuf, ei, rowptr, erec, prel[l], qWbuf);

        // agg = gelu( sum_r wsum_r @ Wv_r ) : per-head batched GEMM, K=256, N=64
        gemm_bf16<64, 2, true, false, false><<<dim3(1, mt128, NH), blk, 0, stream>>>(
            (const void*)qWbuf, 2048, 256, WvT[l], 256, (size_t)64 * 256, nullptr,
            aggb, 512, 64, NN, 256, nullptr, nullptr);

        // out = agg @ Wout + bout (+ skip mix on layer 1)
        if (l == 0)
            gemm_bf16<128, 0, true, true, false><<<dim3(4, mt128), blk, 0, stream>>>(
                (const void*)aggb, 512, 0, WoutT[0], 512, 0, bout[0], h0b, 512, 0, NN, 512, nullptr, nullptr);
        else
            gemm_bf16<128, 0, true, true, true><<<dim3(4, mt128), blk, 0, stream>>>(
                (const void*)aggb, 512, 0, WoutT[1], 512, 0, bout[1], h1b, 512, 0, NN, 512, h0b, skip1);
    }

    // node_embeds = h1 @ Wfc + bfc (f32 out)
    gemm_bf16<128, 0, false, true, false><<<dim3(2, mt128), blk, 0, stream>>>(
        (const void*)h1b, 512, 0, WfcT, 512, 0, bfc, outf, 256, 0, NN, 512, nullptr, nullptr);

    // edge_embeds = relu(ea @ We1 + be1) @ We2 + be2 — fused, 64-row / 8-wave blocks (2x occupancy)
    edge_mlp<<<MEDGE / 64, dim3(512), 0, stream>>>(ea, We1T, be1, We2T, be2, outf + 5120000);
}